// Round 13
// baseline (353.958 us; speedup 1.0000x reference)
//
#include <hip/hip_runtime.h>
#include <cstdint>
#include <cstddef>

typedef float v4f __attribute__((ext_vector_type(4)));
typedef float v2f __attribute__((ext_vector_type(2)));
typedef short v8s __attribute__((ext_vector_type(8)));
typedef unsigned short v4u __attribute__((ext_vector_type(4)));

typedef unsigned short ubf;   // raw bf16 bits

#define NPTS 16384
#define CD   256
#define NBAT 4
#define NPB  4096

__device__ __forceinline__ float bf2f(ubf u) {
    union { unsigned u; float f; } c; c.u = ((unsigned)u) << 16; return c.f;
}
__device__ __forceinline__ ubf f2bf(float f) {
    union { float f; unsigned u; } c; c.f = f;
    unsigned u = c.u;
    u += 0x7fffu + ((u >> 16) & 1u);           // round-nearest-even
    return (ubf)(u >> 16);
}

// -------- fused pre-pass: weight transpose (blocks >= 4096) + point attention
__global__ __launch_bounds__(256) void k_pre(
    const float* __restrict__ low, float* __restrict__ xout,
    const float* __restrict__ bott, const float* __restrict__ qkv,
    const float* __restrict__ mlp, const float* __restrict__ fus,
    ubf* __restrict__ wt) {
    const int bid = blockIdx.x;
    if (bid < 4096) {
        // ---- Point_Attentation ----
        const int lane = threadIdx.x & 63;
        const int row  = bid * 4 + (threadIdx.x >> 6);
        const float* p = low + (size_t)row * CD + lane * 4;
        v4f v = *reinterpret_cast<const v4f*>(p);
        float d[4];
        float s = v[0] + v[1] + v[2] + v[3];
#pragma unroll
        for (int o = 32; o >= 1; o >>= 1) s += __shfl_xor(s, o);
        const float mean = s * (1.0f / 256.0f);
        float ss = 0.f;
#pragma unroll
        for (int i = 0; i < 4; ++i) { d[i] = v[i] - mean; ss += d[i] * d[i]; }
#pragma unroll
        for (int o = 32; o >= 1; o >>= 1) ss += __shfl_xor(ss, o);
        const float var = ss * (1.0f / 4095.0f);    // reference: /(n-1), n=4096
        const float dn  = 1.0f / (4.0f * (var + 1e-5f));
        v4f o;
#pragma unroll
        for (int i = 0; i < 4; ++i) {
            const float e   = d[i] * d[i] * dn + 0.5f;
            const float sig = 1.0f / (1.0f + __expf(-e));
            o[i] = v[i] * (1.0f + sig);
        }
        *reinterpret_cast<v4f*>(xout + (size_t)row * CD + lane * 4) = o;
        return;
    }
    // ---- weight transpose+convert: W[K][256] f32 -> WT[256][K] bf16 ----
    const int bid2 = bid - 4096;
    const int z = bid2 >> 7, r = bid2 & 127;
    const float* src; int K; size_t doff;
    if (z < 6)       { src = bott + (size_t)z * 65536;       K = 256; doff = (size_t)z * 65536; }
    else if (z < 9)  { src = qkv  + (size_t)(z - 6) * 65536; K = 256; doff = (size_t)z * 65536; }
    else if (z < 11) { src = mlp  + (size_t)(z - 9) * 65536; K = 256; doff = (size_t)z * 65536; }
    else             { src = fus;                            K = 512; doff = (size_t)11 * 65536; }
    const int kt = (r >> 3) * 32, nt = (r & 7) * 32;
    if (kt >= K) return;
    __shared__ ubf tile[32][33];
    const int tx = threadIdx.x & 31, ty = threadIdx.x >> 5;   // 32 x 8
#pragma unroll
    for (int i = 0; i < 4; ++i)
        tile[ty * 4 + i][tx] = f2bf(src[(size_t)(kt + ty * 4 + i) * 256 + nt + tx]);
    __syncthreads();
    ubf* dst = wt + doff;
#pragma unroll
    for (int i = 0; i < 4; ++i)
        dst[(size_t)(nt + ty * 4 + i) * K + kt + tx] = tile[tx][ty * 4 + i];
}

// ---------------- k_mid: conv1 (512 blocks, 32-row tiles) ∥ KV-proj (512) ----
// conv1 LDS 48KB -> 3 blocks/CU; kv-proj blocks fill conv1's barrier stalls.
__global__ __launch_bounds__(256) void k_mid(
    float* __restrict__ xA, const float* __restrict__ fh, const ubf* __restrict__ wT,
    const float* __restrict__ bb, const float* __restrict__ bg,
    const float* __restrict__ bbe, const float* __restrict__ bm_,
    const float* __restrict__ bv,
    const float* __restrict__ qg, const float* __restrict__ qbe,
    const float* __restrict__ qm, const float* __restrict__ qv,
    ubf* __restrict__ kB, ubf* __restrict__ vT) {
    __shared__ __attribute__((aligned(16))) float xls[32 * 256];  // 32KB
    __shared__ __attribute__((aligned(16))) ubf   yls[32 * 256];  // 16KB

    const int lane = threadIdx.x & 63;
    const int w    = threadIdx.x >> 6;
    const int wr = w >> 1, wc = w & 1;
    const int q15 = lane & 15, g = lane >> 4;
    const int bid = blockIdx.x;

    if (bid < 512) {
        // ================= conv1: 3 bottlenecks on a 32-row tile =============
        const int bm = bid * 32;
        {
            float* xsrcb = xA + (size_t)bm * 256;
#pragma unroll
            for (int it = 0; it < 8; ++it) {
                const int L4 = (it * 256 + w * 64) * 4;      // wave-uniform f32 base
                const int Ll = L4 + lane * 4;
                const int row = Ll >> 8, col = (Ll & 255) ^ ((row & 7) << 3);
                __builtin_amdgcn_global_load_lds(
                    (const __attribute__((address_space(1))) unsigned*)(xsrcb + row * 256 + col),
                    (__attribute__((address_space(3))) unsigned*)(xls + L4), 16, 0, 0);
            }
        }
        __syncthreads();

        const int r0l = wr * 16 + q15;
#pragma unroll 1
        for (int s = 0; s < 3; ++s) {
            const ubf* W0 = wT + (size_t)(2 * s) * 65536;
            const ubf* W1 = wT + (size_t)(2 * s + 1) * 65536;

            v4f acc[8];
#pragma unroll
            for (int j = 0; j < 8; ++j)
#pragma unroll
                for (int r = 0; r < 4; ++r) acc[j][r] = 0.f;
            for (int ks = 0; ks < 8; ++ks) {
                const int k0 = ks * 32 + g * 8;
                const float* ap = &xls[r0l * 256 + (k0 ^ ((r0l & 7) << 3))];
                v4f a = *reinterpret_cast<const v4f*>(ap);
                v4f b = *reinterpret_cast<const v4f*>(ap + 4);
                v8s afr;
#pragma unroll
                for (int j = 0; j < 4; ++j) { afr[j] = (short)f2bf(a[j]); afr[j + 4] = (short)f2bf(b[j]); }
                v8s bfr[8];
#pragma unroll
                for (int ni = 0; ni < 8; ++ni)
                    bfr[ni] = *reinterpret_cast<const v8s*>(W0 + (size_t)(wc * 128 + ni * 16 + q15) * 256 + k0);
#pragma unroll
                for (int ni = 0; ni < 8; ++ni)
                    acc[ni] = __builtin_amdgcn_mfma_f32_16x16x32_bf16(afr, bfr[ni], acc[ni], 0, 0, 0);
            }
#pragma unroll
            for (int ni = 0; ni < 8; ++ni) {
                const int col = wc * 128 + ni * 16 + q15;
                const int c0i = 2 * s * 256 + col;
                const float sc  = bg[c0i] * rsqrtf(bv[c0i] + 1e-3f);
                const float tc  = bbe[c0i] - bm_[c0i] * sc;
                const float bia = bb[c0i];
#pragma unroll
                for (int r = 0; r < 4; ++r) {
                    const int row = wr * 16 + g * 4 + r;
                    float z = fmaxf((acc[ni][r] + bia) * sc + tc, 0.f);
                    yls[row * 256 + (col ^ ((row & 7) << 3))] = f2bf(z);
                }
            }
            __syncthreads();

#pragma unroll
            for (int j = 0; j < 8; ++j)
#pragma unroll
                for (int r = 0; r < 4; ++r) acc[j][r] = 0.f;
            for (int ks = 0; ks < 8; ++ks) {
                const int k0 = ks * 32 + g * 8;
                v8s afr = *reinterpret_cast<const v8s*>(&yls[r0l * 256 + (k0 ^ ((r0l & 7) << 3))]);
                v8s bfr[8];
#pragma unroll
                for (int ni = 0; ni < 8; ++ni)
                    bfr[ni] = *reinterpret_cast<const v8s*>(W1 + (size_t)(wc * 128 + ni * 16 + q15) * 256 + k0);
#pragma unroll
                for (int ni = 0; ni < 8; ++ni)
                    acc[ni] = __builtin_amdgcn_mfma_f32_16x16x32_bf16(afr, bfr[ni], acc[ni], 0, 0, 0);
            }
#pragma unroll
            for (int ni = 0; ni < 8; ++ni) {
                const int col = wc * 128 + ni * 16 + q15;
                const int c1i = (2 * s + 1) * 256 + col;
                const float sc  = bg[c1i] * rsqrtf(bv[c1i] + 1e-3f);
                const float tc  = bbe[c1i] - bm_[c1i] * sc;
                const float bia = bb[c1i];
#pragma unroll
                for (int r = 0; r < 4; ++r) {
                    const int row = wr * 16 + g * 4 + r;
                    float z = fmaxf((acc[ni][r] + bia) * sc + tc, 0.f);
                    xls[row * 256 + (col ^ ((row & 7) << 3))] += z;
                }
            }
            __syncthreads();
        }

        {
            float* xdstb = xA + (size_t)bm * 256;
#pragma unroll
            for (int it = 0; it < 8; ++it) {
                const int Ll = (it * 256 + threadIdx.x) * 4;
                const int row = Ll >> 8, cl = Ll & 255;
                *reinterpret_cast<v4f*>(xdstb + row * 256 + (cl ^ ((row & 7) << 3))) =
                    *reinterpret_cast<const v4f*>(xls + Ll);
            }
        }
        return;
    }

    // ================= KV projection (from features_high) ====================
    const int bid2 = bid - 512;
    const int m = bid2 >> 8;                     // 0 -> K (w idx7), 1 -> V (idx8)
    const int sub = bid2 & 255;
    const int bm = (sub >> 1) * 128, bn = (sub & 1) * 128;
    const ubf* WT = wT + (size_t)(7 + m) * 65536;
    const float* gamma = qg  + (1 + m) * 256;
    const float* beta  = qbe + (1 + m) * 256;
    const float* bmean = qm  + (1 + m) * 256;
    const float* bvar  = qv  + (1 + m) * 256;
    const int r0 = bm + wr * 64 + q15;
    const int c0 = bn + wc * 64 + q15;

    v4f acc[4][4];
#pragma unroll
    for (int i = 0; i < 4; ++i)
#pragma unroll
        for (int j = 0; j < 4; ++j)
#pragma unroll
            for (int r = 0; r < 4; ++r) acc[i][j][r] = 0.f;

    for (int ks = 0; ks < 8; ++ks) {
        const int k0 = ks * 32 + g * 8;
        v8s afr[4], bfr[4];
#pragma unroll
        for (int mi = 0; mi < 4; ++mi) {
            const float* ap = fh + (size_t)(r0 + mi * 16) * CD + k0;
            v4f a = *reinterpret_cast<const v4f*>(ap);
            v4f b = *reinterpret_cast<const v4f*>(ap + 4);
            v8s t;
#pragma unroll
            for (int j = 0; j < 4; ++j) { t[j] = (short)f2bf(a[j]); t[j + 4] = (short)f2bf(b[j]); }
            afr[mi] = t;
        }
#pragma unroll
        for (int ni = 0; ni < 4; ++ni)
            bfr[ni] = *reinterpret_cast<const v8s*>(WT + (size_t)(c0 + ni * 16) * 256 + k0);
#pragma unroll
        for (int mi = 0; mi < 4; ++mi)
#pragma unroll
            for (int ni = 0; ni < 4; ++ni)
                acc[mi][ni] = __builtin_amdgcn_mfma_f32_16x16x32_bf16(afr[mi], bfr[ni], acc[mi][ni], 0, 0, 0);
    }

#pragma unroll
    for (int ni = 0; ni < 4; ++ni) {
        const int col = c0 + ni * 16;
        const float sc = gamma[col] * rsqrtf(bvar[col] + 1e-3f);
        const float tc = beta[col] - bmean[col] * sc;
#pragma unroll
        for (int mi = 0; mi < 4; ++mi) {
            if (m == 1) {                        // V -> transposed vT[b][c][key]
                const int row0 = bm + wr * 64 + mi * 16 + g * 4;
                v4u pk;
#pragma unroll
                for (int r = 0; r < 4; ++r) pk[r] = f2bf(acc[mi][ni][r] * sc + tc);
                const int bb2 = row0 >> 12, key = row0 & 4095;
                *reinterpret_cast<v4u*>(vT + ((size_t)(bb2 * CD + col)) * NPB + key) = pk;
            } else {
#pragma unroll
                for (int r = 0; r < 4; ++r) {
                    const int row = bm + wr * 64 + mi * 16 + g * 4 + r;
                    kB[(size_t)row * CD + col] = f2bf(acc[mi][ni][r] * sc + tc);
                }
            }
        }
    }
}

// ---------------- q projection (needs conv1 output) --------------------------
__global__ __launch_bounds__(256) void k_qproj(
    const float* __restrict__ xA, const ubf* __restrict__ wT,
    const float* __restrict__ qg, const float* __restrict__ qbe,
    const float* __restrict__ qm, const float* __restrict__ qv,
    ubf* __restrict__ qB) {
    const int lane = threadIdx.x & 63;
    const int w    = threadIdx.x >> 6;
    const int wr = w >> 1, wc = w & 1;
    const int q15 = lane & 15, g = lane >> 4;
    const int bm = blockIdx.x * 128, bn = blockIdx.y * 128;
    const int r0 = bm + wr * 64 + q15;
    const int c0 = bn + wc * 64 + q15;
    const ubf* WT = wT + (size_t)6 * 65536;

    v4f acc[4][4];
#pragma unroll
    for (int i = 0; i < 4; ++i)
#pragma unroll
        for (int j = 0; j < 4; ++j)
#pragma unroll
            for (int r = 0; r < 4; ++r) acc[i][j][r] = 0.f;

    for (int ks = 0; ks < 8; ++ks) {
        const int k0 = ks * 32 + g * 8;
        v8s afr[4], bfr[4];
#pragma unroll
        for (int mi = 0; mi < 4; ++mi) {
            const float* ap = xA + (size_t)(r0 + mi * 16) * CD + k0;
            v4f a = *reinterpret_cast<const v4f*>(ap);
            v4f b = *reinterpret_cast<const v4f*>(ap + 4);
            v8s t;
#pragma unroll
            for (int j = 0; j < 4; ++j) { t[j] = (short)f2bf(a[j]); t[j + 4] = (short)f2bf(b[j]); }
            afr[mi] = t;
        }
#pragma unroll
        for (int ni = 0; ni < 4; ++ni)
            bfr[ni] = *reinterpret_cast<const v8s*>(WT + (size_t)(c0 + ni * 16) * 256 + k0);
#pragma unroll
        for (int mi = 0; mi < 4; ++mi)
#pragma unroll
            for (int ni = 0; ni < 4; ++ni)
                acc[mi][ni] = __builtin_amdgcn_mfma_f32_16x16x32_bf16(afr[mi], bfr[ni], acc[mi][ni], 0, 0, 0);
    }

#pragma unroll
    for (int ni = 0; ni < 4; ++ni) {
        const int col = c0 + ni * 16;
        const float sc = qg[col] * rsqrtf(qv[col] + 1e-3f);
        const float tc = qbe[col] - qm[col] * sc;
#pragma unroll
        for (int mi = 0; mi < 4; ++mi)
#pragma unroll
            for (int r = 0; r < 4; ++r) {
                const int row = bm + wr * 64 + mi * 16 + g * 4 + r;
                qB[(size_t)row * CD + col] = f2bf(acc[mi][ni][r] * sc + tc);
            }
    }
}

// ---- async stages (256-thread block, 4 waves) -------------------------------
__device__ __forceinline__ void stage_k256(const ubf* __restrict__ kg,
                                           ubf* kd, int wave, int lane) {
#pragma unroll
    for (int it = 0; it < 8; ++it) {
        const int Lb = it * 2048 + wave * 512;
        const int L  = Lb + lane * 8;
        const int key = L >> 8, c8 = (L & 255) ^ ((key & 7) << 3);
        __builtin_amdgcn_global_load_lds(
            (const __attribute__((address_space(1))) unsigned*)(kg + key * CD + c8),
            (__attribute__((address_space(3))) unsigned*)(kd + Lb), 16, 0, 0);
    }
}
__device__ __forceinline__ void stage_v256(const ubf* __restrict__ vg,
                                           ubf* vd, int wave, int lane) {
#pragma unroll
    for (int it = 0; it < 8; ++it) {
        const int Lb = it * 2048 + wave * 512;
        const int L  = Lb + lane * 8;
        const int c = L >> 6, k8 = (L & 63) ^ ((c & 7) << 3);
        __builtin_amdgcn_global_load_lds(
            (const __attribute__((address_space(1))) unsigned*)(vg + (size_t)c * NPB + k8),
            (__attribute__((address_space(3))) unsigned*)(vd + Lb), 16, 0, 0);
    }
}

// ---------------- flash attention: 32 q-rows/wave, KV-split x2 ---------------
// 256 blocks x 256 thr. Block (b, half, qt): 128 q-rows (4 waves x 32 as two
// 16-row sets sharing each K/V LDS fragment -> LDS traffic per q-row halves),
// keys [half*2048, +2048) in 32 chunks of 64. LDS = K 32K + V 32K + P 16K.
// Overlapped staging: V(kc) issued before QK, K(kc+1) after the QK barrier.
__global__ __launch_bounds__(256, 1) void k_attn(const ubf* __restrict__ qb, const ubf* __restrict__ kb,
                                                 const ubf* __restrict__ vt,
                                                 ubf* __restrict__ o0, ubf* __restrict__ o1,
                                                 float* __restrict__ ml) {
    __shared__ __attribute__((aligned(16))) ubf kls[64 * 256];      // 32KB
    __shared__ __attribute__((aligned(16))) ubf vls[256 * 64];      // 32KB (V^T)
    __shared__ __attribute__((aligned(16))) ubf pls[4 * 2 * 1024];  // 16KB per-wave/set P

    const int raw = blockIdx.x;                  // XCD swizzle: xcd = (b<<1)|half
    const int xcd = raw & 7, qt = raw >> 3;      // qt 0..31
    const int b = xcd >> 1, half = xcd & 1;

    const int wave = threadIdx.x >> 6, lane = threadIdx.x & 63;
    const int q15 = lane & 15, g = lane >> 4;
    const int swzP = (q15 & 7) << 3;

    // Q fragments, two 16-row sets per wave
    v8s qf[2][8];
#pragma unroll
    for (int s = 0; s < 2; ++s) {
        const ubf* qrow = qb + ((size_t)(b * NPB + qt * 128 + wave * 32 + s * 16 + q15)) * CD + g * 8;
#pragma unroll
        for (int cs = 0; cs < 8; ++cs) qf[s][cs] = *reinterpret_cast<const v8s*>(qrow + cs * 32);
    }

    v4f oacc[2][16];
#pragma unroll
    for (int s = 0; s < 2; ++s)
#pragma unroll
        for (int i = 0; i < 16; ++i)
#pragma unroll
            for (int r = 0; r < 4; ++r) oacc[s][i][r] = 0.f;
    float m_run[2] = { -3.0e38f, -3.0e38f }, l_run[2] = { 0.f, 0.f };

    const ubf* kgb = kb + ((size_t)(b * NPB) + half * 2048) * CD;
    const ubf* vgb = vt + (size_t)b * CD * NPB + half * 2048;
    ubf* pw = pls + wave * 2048;

    stage_k256(kgb, kls, wave, lane);
    __syncthreads();                             // K(0) ready

    for (int kc = 0; kc < 32; ++kc) {
        stage_v256(vgb + kc * 64, vls, wave, lane);   // V(kc) in flight

        // S' = K_chunk @ Q^T for both q-sets (af shared)
        v4f sacc[2][4];
#pragma unroll
        for (int s = 0; s < 2; ++s)
#pragma unroll
            for (int f = 0; f < 4; ++f)
#pragma unroll
                for (int r = 0; r < 4; ++r) sacc[s][f][r] = 0.f;
#pragma unroll
        for (int cs = 0; cs < 8; ++cs)
#pragma unroll
            for (int f = 0; f < 4; ++f) {
                const int key = 16 * f + q15;
                v8s af = *reinterpret_cast<const v8s*>(&kls[(key * CD + cs * 32 + g * 8) ^ ((key & 7) << 3)]);
                sacc[0][f] = __builtin_amdgcn_mfma_f32_16x16x32_bf16(af, qf[0][cs], sacc[0][f], 0, 0, 0);
                sacc[1][f] = __builtin_amdgcn_mfma_f32_16x16x32_bf16(af, qf[1][cs], sacc[1][f], 0, 0, 0);
            }

        __syncthreads();                         // drains V(kc); kls reads done
        if (kc + 1 < 32)
            stage_k256(kgb + (size_t)(kc + 1) * 64 * CD, kls, wave, lane);

        // online softmax per set (defer-rescale THR=8)
#pragma unroll
        for (int s = 0; s < 2; ++s) {
            float mloc = -3.0e38f;
#pragma unroll
            for (int f = 0; f < 4; ++f)
#pragma unroll
                for (int r = 0; r < 4; ++r) {
                    float x = sacc[s][f][r] * 0.0625f;
                    sacc[s][f][r] = x;
                    mloc = fmaxf(mloc, x);
                }
            mloc = fmaxf(mloc, __shfl_xor(mloc, 16));
            mloc = fmaxf(mloc, __shfl_xor(mloc, 32));
            if (!__all(mloc <= m_run[s] + 8.0f)) {
                const float mnew  = fmaxf(m_run[s], mloc);
                const float alpha = __expf(m_run[s] - mnew);
                l_run[s] *= alpha;
#pragma unroll
                for (int i = 0; i < 16; ++i)
#pragma unroll
                    for (int r = 0; r < 4; ++r) oacc[s][i][r] *= alpha;
                m_run[s] = mnew;
            }
            float lloc = 0.f;
#pragma unroll
            for (int f = 0; f < 4; ++f)
#pragma unroll
                for (int r = 0; r < 4; ++r) {
                    float p = __expf(sacc[s][f][r] - m_run[s]);
                    sacc[s][f][r] = p;
                    lloc += p;
                }
            lloc += __shfl_xor(lloc, 16);
            lloc += __shfl_xor(lloc, 32);
            l_run[s] += lloc;

            // P -> LDS (bf16 trunc), per-wave/set region
#pragma unroll
            for (int f = 0; f < 4; ++f) {
                unsigned u0, u1, u2, u3;
                { union { float f; unsigned u; } c; c.f = sacc[s][f][0]; u0 = c.u; }
                { union { float f; unsigned u; } c; c.f = sacc[s][f][1]; u1 = c.u; }
                { union { float f; unsigned u; } c; c.f = sacc[s][f][2]; u2 = c.u; }
                { union { float f; unsigned u; } c; c.f = sacc[s][f][3]; u3 = c.u; }
                unsigned p01 = (u0 >> 16) | (u1 & 0xFFFF0000u);
                unsigned p23 = (u2 >> 16) | (u3 & 0xFFFF0000u);
                const int e = s * 1024 + q15 * 64 + 16 * f + 4 * g;
                *reinterpret_cast<unsigned*>(&pw[(e)     ^ swzP]) = p01;
                *reinterpret_cast<unsigned*>(&pw[(e + 2) ^ swzP]) = p23;
            }
        }

        // O^T += V^T_chunk @ P (av shared between sets)
        v8s pb0[2], pb1[2];
#pragma unroll
        for (int s = 0; s < 2; ++s) {
            pb0[s] = *reinterpret_cast<const v8s*>(&pw[(s * 1024 + q15 * 64 +  0 + 8 * g) ^ swzP]);
            pb1[s] = *reinterpret_cast<const v8s*>(&pw[(s * 1024 + q15 * 64 + 32 + 8 * g) ^ swzP]);
        }
#pragma unroll
        for (int mt = 0; mt < 16; ++mt) {
            const int c = 16 * mt + q15;
            v8s av0 = *reinterpret_cast<const v8s*>(&vls[(c * 64 +  0 + 8 * g) ^ ((c & 7) << 3)]);
            oacc[0][mt] = __builtin_amdgcn_mfma_f32_16x16x32_bf16(av0, pb0[0], oacc[0][mt], 0, 0, 0);
            oacc[1][mt] = __builtin_amdgcn_mfma_f32_16x16x32_bf16(av0, pb0[1], oacc[1][mt], 0, 0, 0);
            v8s av1 = *reinterpret_cast<const v8s*>(&vls[(c * 64 + 32 + 8 * g) ^ ((c & 7) << 3)]);
            oacc[0][mt] = __builtin_amdgcn_mfma_f32_16x16x32_bf16(av1, pb1[0], oacc[0][mt], 0, 0, 0);
            oacc[1][mt] = __builtin_amdgcn_mfma_f32_16x16x32_bf16(av1, pb1[1], oacc[1][mt], 0, 0, 0);
        }

        __syncthreads();   // drains K(kc+1); vls reads done before next V stage
    }

    // epilogue: unnormalized partial O (bf16) + per-row (m, l)
#pragma unroll
    for (int s = 0; s < 2; ++s) {
        const int grow = b * NPB + qt * 128 + wave * 32 + s * 16 + q15;
        ubf* aor = (half ? o1 : o0) + (size_t)grow * CD;
#pragma unroll
        for (int mt = 0; mt < 16; ++mt) {
            v4u pk;
#pragma unroll
            for (int r = 0; r < 4; ++r) pk[r] = f2bf(oacc[s][mt][r]);
            *reinterpret_cast<v4u*>(aor + 16 * mt + 4 * g) = pk;
        }
        if (g == 0) {
            v2f d; d[0] = m_run[s]; d[1] = l_run[s];
            *reinterpret_cast<v2f*>(ml + (size_t)(half * NPTS + grow) * 2) = d;
        }
    }
}

// ---------------- fused tail: merge+mlp1 -> mlp2 -> fusion (K=512) -----------
__global__ __launch_bounds__(256) void k_tail(
    const ubf* __restrict__ o0, const ubf* __restrict__ o1, const float* __restrict__ ml,
    const float* __restrict__ xA, const ubf* __restrict__ wT,
    const float* __restrict__ mg, const float* __restrict__ mbe,
    const float* __restrict__ mm, const float* __restrict__ mv,
    const float* __restrict__ fb, const float* __restrict__ fg,
    const float* __restrict__ fbe, const float* __restrict__ fm,
    const float* __restrict__ fv, float* __restrict__ out) {
    __shared__ __attribute__((aligned(16))) ubf yls[64 * 256];   // 32KB

    const int lane = threadIdx.x & 63;
    const int w    = threadIdx.x >> 6;
    const int wr = w >> 1, wc = w & 1;
    const int q15 = lane & 15, g = lane >> 4;
    const int bm = blockIdx.x * 64;
    const int r0l = wr * 32 + q15;

    const ubf* W9  = wT + (size_t)9 * 65536;
    const ubf* W10 = wT + (size_t)10 * 65536;
    const ubf* W11 = wT + (size_t)11 * 65536;

    v4f acc[2][8];

    float a0[2], a1[2];
#pragma unroll
    for (int mi = 0; mi < 2; ++mi) {
        const int row = bm + r0l + mi * 16;
        const float m0 = ml[2 * row],          l0 = ml[2 * row + 1];
        const float m1 = ml[2 * (NPTS + row)], l1 = ml[2 * (NPTS + row) + 1];
        const float mx = fmaxf(m0, m1);
        const float w0 = __expf(m0 - mx), w1 = __expf(m1 - mx);
        const float inv = 1.0f / (w0 * l0 + w1 * l1);
        a0[mi] = w0 * inv; a1[mi] = w1 * inv;
    }
#pragma unroll
    for (int i = 0; i < 2; ++i)
#pragma unroll
        for (int j = 0; j < 8; ++j)
#pragma unroll
            for (int r = 0; r < 4; ++r) acc[i][j][r] = 0.f;
    for (int ks = 0; ks < 8; ++ks) {
        const int k0 = ks * 32 + g * 8;
        v8s afr[2], bfr[8];
#pragma unroll
        for (int mi = 0; mi < 2; ++mi) {
            const int row = bm + r0l + mi * 16;
            v8s u0 = *reinterpret_cast<const v8s*>(o0 + (size_t)row * CD + k0);
            v8s u1 = *reinterpret_cast<const v8s*>(o1 + (size_t)row * CD + k0);
            v8s t;
#pragma unroll
            for (int j = 0; j < 8; ++j)
                t[j] = (short)f2bf(a0[mi] * bf2f((ubf)u0[j]) + a1[mi] * bf2f((ubf)u1[j]));
            afr[mi] = t;
        }
#pragma unroll
        for (int ni = 0; ni < 8; ++ni)
            bfr[ni] = *reinterpret_cast<const v8s*>(W9 + (size_t)(wc * 128 + ni * 16 + q15) * 256 + k0);
#pragma unroll
        for (int mi = 0; mi < 2; ++mi)
#pragma unroll
            for (int ni = 0; ni < 8; ++ni)
                acc[mi][ni] = __builtin_amdgcn_mfma_f32_16x16x32_bf16(afr[mi], bfr[ni], acc[mi][ni], 0, 0, 0);
    }
#pragma unroll
    for (int ni = 0; ni < 8; ++ni) {
        const int col = wc * 128 + ni * 16 + q15;
        const float sc = mg[col] * rsqrtf(mv[col] + 1e-3f);
        const float tc = mbe[col] - mm[col] * sc;
#pragma unroll
        for (int mi = 0; mi < 2; ++mi)
#pragma unroll
            for (int r = 0; r < 4; ++r) {
                const int row = wr * 32 + mi * 16 + g * 4 + r;
                float z = fmaxf(acc[mi][ni][r] * sc + tc, 0.f);
                yls[row * 256 + (col ^ ((row & 7) << 3))] = f2bf(z);
            }
    }
    __syncthreads();

#pragma unroll
    for (int i = 0; i < 2; ++i)
#pragma unroll
        for (int j = 0; j < 8; ++j)
#pragma unroll
            for (int r = 0; r < 4; ++r) acc[i][j][r] = 0.f;
    for (int ks = 0; ks < 8; ++ks) {
        const int k0 = ks * 32 + g * 8;
        v8s afr[2], bfr[8];
#pragma unroll
        for (int mi = 0; mi < 2; ++mi) {
            const int row = r0l + mi * 16;
            afr[mi] = *reinterpret_cast<const v8s*>(&yls[row * 256 + (k0 ^ ((row & 7) << 3))]);
        }
#pragma unroll
        for (int ni = 0; ni < 8; ++ni)
            bfr[ni] = *reinterpret_cast<const v8s*>(W10 + (size_t)(wc * 128 + ni * 16 + q15) * 256 + k0);
#pragma unroll
        for (int mi = 0; mi < 2; ++mi)
#pragma unroll
            for (int ni = 0; ni < 8; ++ni)
                acc[mi][ni] = __builtin_amdgcn_mfma_f32_16x16x32_bf16(afr[mi], bfr[ni], acc[mi][ni], 0, 0, 0);
    }
    __syncthreads();
#pragma unroll
    for (int ni = 0; ni < 8; ++ni) {
        const int col = wc * 128 + ni * 16 + q15;
        const float sc = mg[256 + col] * rsqrtf(mv[256 + col] + 1e-3f);
        const float tc = mbe[256 + col] - mm[256 + col] * sc;
#pragma unroll
        for (int mi = 0; mi < 2; ++mi)
#pragma unroll
            for (int r = 0; r < 4; ++r) {
                const int row = wr * 32 + mi * 16 + g * 4 + r;
                float z = fmaxf(acc[mi][ni][r] * sc + tc, 0.f);
                yls[row * 256 + (col ^ ((row & 7) << 3))] = f2bf(z);
            }
    }
    __syncthreads();

#pragma unroll
    for (int i = 0; i < 2; ++i)
#pragma unroll
        for (int j = 0; j < 8; ++j)
#pragma unroll
            for (int r = 0; r < 4; ++r) acc[i][j][r] = 0.f;
    for (int ks = 0; ks < 16; ++ks) {
        const int k0 = ks * 32 + g * 8;
        v8s afr[2], bfr[8];
#pragma unroll
        for (int mi = 0; mi < 2; ++mi) {
            if (k0 < 256) {
                const float* ap = xA + (size_t)(bm + r0l + mi * 16) * CD + k0;
                v4f a = *reinterpret_cast<const v4f*>(ap);
                v4f b = *reinterpret_cast<const v4f*>(ap + 4);
                v8s t;
#pragma unroll
                for (int j = 0; j < 4; ++j) { t[j] = (short)f2bf(a[j]); t[j + 4] = (short)f2bf(b[j]); }
                afr[mi] = t;
            } else {
                const int row = r0l + mi * 16, kk = k0 - 256;
                afr[mi] = *reinterpret_cast<const v8s*>(&yls[row * 256 + (kk ^ ((row & 7) << 3))]);
            }
        }
#pragma unroll
        for (int ni = 0; ni < 8; ++ni)
            bfr[ni] = *reinterpret_cast<const v8s*>(W11 + (size_t)(wc * 128 + ni * 16 + q15) * 512 + k0);
#pragma unroll
        for (int mi = 0; mi < 2; ++mi)
#pragma unroll
            for (int ni = 0; ni < 8; ++ni)
                acc[mi][ni] = __builtin_amdgcn_mfma_f32_16x16x32_bf16(afr[mi], bfr[ni], acc[mi][ni], 0, 0, 0);
    }
#pragma unroll
    for (int ni = 0; ni < 8; ++ni) {
        const int col = wc * 128 + ni * 16 + q15;
        const float sc = fg[col] * rsqrtf(fv[col] + 1e-3f);
        const float tc = fbe[col] - fm[col] * sc;
        const float bia = fb[col];
#pragma unroll
        for (int mi = 0; mi < 2; ++mi)
#pragma unroll
            for (int r = 0; r < 4; ++r) {
                const int row = bm + wr * 32 + mi * 16 + g * 4 + r;
                float z = fmaxf((acc[mi][ni][r] + bia) * sc + tc, 0.f);
                out[(size_t)row * CD + col] = z;
            }
    }
}

// ---------------- launcher ---------------------------------------------------
extern "C" void kernel_launch(void* const* d_in, const int* in_sizes, int n_in,
                              void* d_out, int out_size, void* d_ws, size_t ws_size,
                              hipStream_t stream) {
    const float* f_low   = (const float*)d_in[0];
    const float* f_high  = (const float*)d_in[1];
    const float* bott_W  = (const float*)d_in[2];
    const float* bott_b  = (const float*)d_in[3];
    const float* bott_g  = (const float*)d_in[4];
    const float* bott_be = (const float*)d_in[5];
    const float* bott_m  = (const float*)d_in[6];
    const float* bott_v  = (const float*)d_in[7];
    const float* qkv_W   = (const float*)d_in[8];
    const float* qkv_g   = (const float*)d_in[9];
    const float* qkv_be  = (const float*)d_in[10];
    const float* qkv_m   = (const float*)d_in[11];
    const float* qkv_v   = (const float*)d_in[12];
    const float* mlp_W   = (const float*)d_in[13];
    const float* mlp_g   = (const float*)d_in[14];
    const float* mlp_be  = (const float*)d_in[15];
    const float* mlp_m   = (const float*)d_in[16];
    const float* mlp_v   = (const float*)d_in[17];
    const float* fus_W   = (const float*)d_in[18];
    const float* fus_b   = (const float*)d_in[19];
    const float* fus_g   = (const float*)d_in[20];
    const float* fus_be  = (const float*)d_in[21];
    const float* fus_m   = (const float*)d_in[22];
    const float* fus_v   = (const float*)d_in[23];
    (void)in_sizes; (void)n_in; (void)out_size; (void)ws_size;

    char* ws = (char*)d_ws;
    const size_t MB = 1024 * 1024;
    float* xA = (float*)(ws);                       // 16.8 MB residual stream
    ubf*   o0 = (ubf*)  (ws + 17 * MB);             // 8.4 MB attn half0 partial
    ubf*   qB = (ubf*)  (ws + 26 * MB);             // 8.4 MB Q
    ubf*   kB = (ubf*)  (ws + 35 * MB);             // 8.4 MB K
    ubf*   vT = (ubf*)  (ws + 44 * MB);             // 8.4 MB V^T [B][C][n]
    ubf*   wT = (ubf*)  (ws + 53 * MB);             // 1.7 MB, 12 transposed weights
    ubf*   o1 = (ubf*)  (ws + 56 * MB);             // 8.4 MB attn half1 partial
    float* ml = (float*)(ws + 65 * MB);             // 512 KB (m,l) x 2 halves

    k_pre<<<dim3(4096 + 1536), dim3(256), 0, stream>>>(f_low, xA,
                                                       bott_W, qkv_W, mlp_W, fus_W, wT);

    k_mid<<<dim3(1024), dim3(256), 0, stream>>>(xA, f_high, wT,
                                                bott_b, bott_g, bott_be, bott_m, bott_v,
                                                qkv_g, qkv_be, qkv_m, qkv_v, kB, vT);

    k_qproj<<<dim3(128, 2), dim3(256), 0, stream>>>(xA, wT, qkv_g, qkv_be, qkv_m, qkv_v, qB);

    k_attn<<<dim3(256), dim3(256), 0, stream>>>(qB, kB, vT, o0, o1, ml);

    k_tail<<<dim3(256), dim3(256), 0, stream>>>(o0, o1, ml, xA, wT,
                                                mlp_g, mlp_be, mlp_m, mlp_v,
                                                fus_b, fus_g, fus_be, fus_m, fus_v,
                                                (float*)d_out);
}

// Round 14
// 305.527 us; speedup vs baseline: 1.1585x; 1.1585x over previous
//
#include <hip/hip_runtime.h>
#include <cstdint>
#include <cstddef>

typedef float v4f __attribute__((ext_vector_type(4)));
typedef float v2f __attribute__((ext_vector_type(2)));
typedef short v8s __attribute__((ext_vector_type(8)));
typedef unsigned short v4u __attribute__((ext_vector_type(4)));

typedef unsigned short ubf;   // raw bf16 bits

#define NPTS 16384
#define CD   256
#define NBAT 4
#define NPB  4096

__device__ __forceinline__ float bf2f(ubf u) {
    union { unsigned u; float f; } c; c.u = ((unsigned)u) << 16; return c.f;
}
__device__ __forceinline__ ubf f2bf(float f) {
    union { float f; unsigned u; } c; c.f = f;
    unsigned u = c.u;
    u += 0x7fffu + ((u >> 16) & 1u);           // round-nearest-even
    return (ubf)(u >> 16);
}

// -------- fused pre-pass: weight transpose (blocks >= 4096) + point attention
__global__ __launch_bounds__(256) void k_pre(
    const float* __restrict__ low, float* __restrict__ xout,
    const float* __restrict__ bott, const float* __restrict__ qkv,
    const float* __restrict__ mlp, const float* __restrict__ fus,
    ubf* __restrict__ wt) {
    const int bid = blockIdx.x;
    if (bid < 4096) {
        // ---- Point_Attentation ----
        const int lane = threadIdx.x & 63;
        const int row  = bid * 4 + (threadIdx.x >> 6);
        const float* p = low + (size_t)row * CD + lane * 4;
        v4f v = *reinterpret_cast<const v4f*>(p);
        float d[4];
        float s = v[0] + v[1] + v[2] + v[3];
#pragma unroll
        for (int o = 32; o >= 1; o >>= 1) s += __shfl_xor(s, o);
        const float mean = s * (1.0f / 256.0f);
        float ss = 0.f;
#pragma unroll
        for (int i = 0; i < 4; ++i) { d[i] = v[i] - mean; ss += d[i] * d[i]; }
#pragma unroll
        for (int o = 32; o >= 1; o >>= 1) ss += __shfl_xor(ss, o);
        const float var = ss * (1.0f / 4095.0f);    // reference: /(n-1), n=4096
        const float dn  = 1.0f / (4.0f * (var + 1e-5f));
        v4f o;
#pragma unroll
        for (int i = 0; i < 4; ++i) {
            const float e   = d[i] * d[i] * dn + 0.5f;
            const float sig = 1.0f / (1.0f + __expf(-e));
            o[i] = v[i] * (1.0f + sig);
        }
        *reinterpret_cast<v4f*>(xout + (size_t)row * CD + lane * 4) = o;
        return;
    }
    // ---- weight transpose+convert: W[K][256] f32 -> WT[256][K] bf16 ----
    const int bid2 = bid - 4096;
    const int z = bid2 >> 7, r = bid2 & 127;
    const float* src; int K; size_t doff;
    if (z < 6)       { src = bott + (size_t)z * 65536;       K = 256; doff = (size_t)z * 65536; }
    else if (z < 9)  { src = qkv  + (size_t)(z - 6) * 65536; K = 256; doff = (size_t)z * 65536; }
    else if (z < 11) { src = mlp  + (size_t)(z - 9) * 65536; K = 256; doff = (size_t)z * 65536; }
    else             { src = fus;                            K = 512; doff = (size_t)11 * 65536; }
    const int kt = (r >> 3) * 32, nt = (r & 7) * 32;
    if (kt >= K) return;
    __shared__ ubf tile[32][33];
    const int tx = threadIdx.x & 31, ty = threadIdx.x >> 5;   // 32 x 8
#pragma unroll
    for (int i = 0; i < 4; ++i)
        tile[ty * 4 + i][tx] = f2bf(src[(size_t)(kt + ty * 4 + i) * 256 + nt + tx]);
    __syncthreads();
    ubf* dst = wt + doff;
#pragma unroll
    for (int i = 0; i < 4; ++i)
        dst[(size_t)(nt + ty * 4 + i) * K + kt + tx] = tile[tx][ty * 4 + i];
}

// ---------------- fused conv1: 3 bottlenecks (6 GEMMs) in one dispatch -------
// grid 256, block 256 (4 waves 2x2). Per block: 64-row tile. (r11-proven)
__global__ __launch_bounds__(256) void k_conv1(
    float* __restrict__ xA, const ubf* __restrict__ wT,
    const float* __restrict__ bb, const float* __restrict__ bg,
    const float* __restrict__ bbe, const float* __restrict__ bm_,
    const float* __restrict__ bv) {
    __shared__ __attribute__((aligned(16))) float xls[64 * 256];  // 64KB
    __shared__ __attribute__((aligned(16))) ubf   yls[64 * 256];  // 32KB

    const int lane = threadIdx.x & 63;
    const int w    = threadIdx.x >> 6;
    const int wr = w >> 1, wc = w & 1;
    const int q15 = lane & 15, g = lane >> 4;
    const int bm = blockIdx.x * 64;

    {
        float* xsrcb = xA + (size_t)bm * 256;
#pragma unroll
        for (int it = 0; it < 16; ++it) {
            const int L4 = (it * 256 + w * 64) * 4;      // wave-uniform f32 base
            const int Ll = L4 + lane * 4;
            const int row = Ll >> 8, col = (Ll & 255) ^ ((row & 7) << 3);
            __builtin_amdgcn_global_load_lds(
                (const __attribute__((address_space(1))) unsigned*)(xsrcb + row * 256 + col),
                (__attribute__((address_space(3))) unsigned*)(xls + L4), 16, 0, 0);
        }
    }
    __syncthreads();

    const int r0l = wr * 32 + q15;
#pragma unroll 1
    for (int s = 0; s < 3; ++s) {
        const ubf* W0 = wT + (size_t)(2 * s) * 65536;
        const ubf* W1 = wT + (size_t)(2 * s + 1) * 65536;

        v4f acc[2][8];
#pragma unroll
        for (int i = 0; i < 2; ++i)
#pragma unroll
            for (int j = 0; j < 8; ++j)
#pragma unroll
                for (int r = 0; r < 4; ++r) acc[i][j][r] = 0.f;
        for (int ks = 0; ks < 8; ++ks) {
            const int k0 = ks * 32 + g * 8;
            v8s afr[2], bfr[8];
#pragma unroll
            for (int mi = 0; mi < 2; ++mi) {
                const int row = r0l + mi * 16;
                const float* ap = &xls[row * 256 + (k0 ^ ((row & 7) << 3))];
                v4f a = *reinterpret_cast<const v4f*>(ap);
                v4f b = *reinterpret_cast<const v4f*>(ap + 4);
                v8s t;
#pragma unroll
                for (int j = 0; j < 4; ++j) { t[j] = (short)f2bf(a[j]); t[j + 4] = (short)f2bf(b[j]); }
                afr[mi] = t;
            }
#pragma unroll
            for (int ni = 0; ni < 8; ++ni)
                bfr[ni] = *reinterpret_cast<const v8s*>(W0 + (size_t)(wc * 128 + ni * 16 + q15) * 256 + k0);
#pragma unroll
            for (int mi = 0; mi < 2; ++mi)
#pragma unroll
                for (int ni = 0; ni < 8; ++ni)
                    acc[mi][ni] = __builtin_amdgcn_mfma_f32_16x16x32_bf16(afr[mi], bfr[ni], acc[mi][ni], 0, 0, 0);
        }
#pragma unroll
        for (int ni = 0; ni < 8; ++ni) {
            const int col = wc * 128 + ni * 16 + q15;
            const float sc  = bg[2 * s * 256 + col] * rsqrtf(bv[2 * s * 256 + col] + 1e-3f);
            const float tc  = bbe[2 * s * 256 + col] - bm_[2 * s * 256 + col] * sc;
            const float bia = bb[2 * s * 256 + col];
#pragma unroll
            for (int mi = 0; mi < 2; ++mi)
#pragma unroll
                for (int r = 0; r < 4; ++r) {
                    const int row = wr * 32 + mi * 16 + g * 4 + r;
                    float z = fmaxf((acc[mi][ni][r] + bia) * sc + tc, 0.f);
                    yls[row * 256 + (col ^ ((row & 7) << 3))] = f2bf(z);
                }
        }
        __syncthreads();

#pragma unroll
        for (int i = 0; i < 2; ++i)
#pragma unroll
            for (int j = 0; j < 8; ++j)
#pragma unroll
                for (int r = 0; r < 4; ++r) acc[i][j][r] = 0.f;
        for (int ks = 0; ks < 8; ++ks) {
            const int k0 = ks * 32 + g * 8;
            v8s afr[2], bfr[8];
#pragma unroll
            for (int mi = 0; mi < 2; ++mi) {
                const int row = r0l + mi * 16;
                afr[mi] = *reinterpret_cast<const v8s*>(&yls[row * 256 + (k0 ^ ((row & 7) << 3))]);
            }
#pragma unroll
            for (int ni = 0; ni < 8; ++ni)
                bfr[ni] = *reinterpret_cast<const v8s*>(W1 + (size_t)(wc * 128 + ni * 16 + q15) * 256 + k0);
#pragma unroll
            for (int mi = 0; mi < 2; ++mi)
#pragma unroll
                for (int ni = 0; ni < 8; ++ni)
                    acc[mi][ni] = __builtin_amdgcn_mfma_f32_16x16x32_bf16(afr[mi], bfr[ni], acc[mi][ni], 0, 0, 0);
        }
#pragma unroll
        for (int ni = 0; ni < 8; ++ni) {
            const int col = wc * 128 + ni * 16 + q15;
            const int c1 = (2 * s + 1) * 256 + col;
            const float sc  = bg[c1] * rsqrtf(bv[c1] + 1e-3f);
            const float tc  = bbe[c1] - bm_[c1] * sc;
            const float bia = bb[c1];
#pragma unroll
            for (int mi = 0; mi < 2; ++mi)
#pragma unroll
                for (int r = 0; r < 4; ++r) {
                    const int row = wr * 32 + mi * 16 + g * 4 + r;
                    float z = fmaxf((acc[mi][ni][r] + bia) * sc + tc, 0.f);
                    xls[row * 256 + (col ^ ((row & 7) << 3))] += z;
                }
        }
        __syncthreads();
    }

    {
        float* xdstb = xA + (size_t)bm * 256;
#pragma unroll
        for (int it = 0; it < 16; ++it) {
            const int Ll = (it * 256 + threadIdx.x) * 4;
            const int row = Ll >> 8, cl = Ll & 255;
            const int gcol = cl ^ ((row & 7) << 3);
            *reinterpret_cast<v4f*>(xdstb + row * 256 + gcol) =
                *reinterpret_cast<const v4f*>(xls + Ll);
        }
    }
}

// ---------------- fused QKV projection: one dispatch, 768 blocks -------------
__global__ __launch_bounds__(256) void k_qkv(
    const float* __restrict__ xA, const float* __restrict__ fh,
    const ubf* __restrict__ wTq,
    const float* __restrict__ qg, const float* __restrict__ qbe,
    const float* __restrict__ qm, const float* __restrict__ qv,
    ubf* __restrict__ qB, ubf* __restrict__ kB, ubf* __restrict__ vT) {
    const int m = blockIdx.y >> 1;               // 0=q, 1=k, 2=v
    const float* Af = (m == 0) ? xA : fh;
    const ubf* WT = wTq + m * 65536;
    const float* gamma = qg + m * 256;
    const float* beta  = qbe + m * 256;
    const float* bmean = qm + m * 256;
    const float* bvar  = qv + m * 256;

    const int lane = threadIdx.x & 63;
    const int w    = threadIdx.x >> 6;
    const int wr = w >> 1, wc = w & 1;
    const int q15 = lane & 15, g = lane >> 4;
    const int bm = blockIdx.x * 128, bn = (blockIdx.y & 1) * 128;
    const int r0 = bm + wr * 64 + q15;
    const int c0 = bn + wc * 64 + q15;

    v4f acc[4][4];
#pragma unroll
    for (int i = 0; i < 4; ++i)
#pragma unroll
        for (int j = 0; j < 4; ++j)
#pragma unroll
            for (int r = 0; r < 4; ++r) acc[i][j][r] = 0.f;

    for (int ks = 0; ks < 8; ++ks) {
        const int k0 = ks * 32 + g * 8;
        v8s afr[4], bfr[4];
#pragma unroll
        for (int mi = 0; mi < 4; ++mi) {
            const float* ap = Af + (size_t)(r0 + mi * 16) * CD + k0;
            v4f a = *reinterpret_cast<const v4f*>(ap);
            v4f b = *reinterpret_cast<const v4f*>(ap + 4);
            v8s t;
#pragma unroll
            for (int j = 0; j < 4; ++j) { t[j] = (short)f2bf(a[j]); t[j + 4] = (short)f2bf(b[j]); }
            afr[mi] = t;
        }
#pragma unroll
        for (int ni = 0; ni < 4; ++ni)
            bfr[ni] = *reinterpret_cast<const v8s*>(WT + (size_t)(c0 + ni * 16) * 256 + k0);
#pragma unroll
        for (int mi = 0; mi < 4; ++mi)
#pragma unroll
            for (int ni = 0; ni < 4; ++ni)
                acc[mi][ni] = __builtin_amdgcn_mfma_f32_16x16x32_bf16(afr[mi], bfr[ni], acc[mi][ni], 0, 0, 0);
    }

    ubf* outb = (m == 0) ? qB : kB;
#pragma unroll
    for (int ni = 0; ni < 4; ++ni) {
        const int col = c0 + ni * 16;
        const float sc = gamma[col] * rsqrtf(bvar[col] + 1e-3f);
        const float tc = beta[col] - bmean[col] * sc;
#pragma unroll
        for (int mi = 0; mi < 4; ++mi) {
            if (m == 2) {
                const int row0 = bm + wr * 64 + mi * 16 + g * 4;
                v4u pk;
#pragma unroll
                for (int r = 0; r < 4; ++r) pk[r] = f2bf(acc[mi][ni][r] * sc + tc);
                const int bb = row0 >> 12, key = row0 & 4095;
                *reinterpret_cast<v4u*>(vT + ((size_t)(bb * CD + col)) * NPB + key) = pk;
            } else {
#pragma unroll
                for (int r = 0; r < 4; ++r) {
                    const int row = bm + wr * 64 + mi * 16 + g * 4 + r;
                    outb[(size_t)row * CD + col] = f2bf(acc[mi][ni][r] * sc + tc);
                }
            }
        }
    }
}

// ---- async stages (128-thread block, 2 waves), KVBLK = 32 -------------------
// K chunk [32][256] (16KB), row col-swizzle ^((key&7)<<3).
// V^T chunk packed: c-pairs into 64-elem rows, swizzle ^(((c>>1)&7)<<3) (16KB).
__device__ __forceinline__ void stage_k32(const ubf* __restrict__ kg,
                                          ubf* kd, int wave, int lane) {
#pragma unroll
    for (int it = 0; it < 8; ++it) {
        const int Lb = it * 1024 + wave * 512;
        const int L  = Lb + lane * 8;
        const int key = L >> 8, c8 = (L & 255) ^ ((key & 7) << 3);
        __builtin_amdgcn_global_load_lds(
            (const __attribute__((address_space(1))) unsigned*)(kg + key * CD + c8),
            (__attribute__((address_space(3))) unsigned*)(kd + Lb), 16, 0, 0);
    }
}
__device__ __forceinline__ void stage_v32(const ubf* __restrict__ vg,
                                          ubf* vd, int wave, int lane) {
#pragma unroll
    for (int it = 0; it < 8; ++it) {
        const int Lb = it * 1024 + wave * 512;
        const int L  = Lb + lane * 8;
        const int cpair = L >> 6;
        const int rem   = (L & 63) ^ ((cpair & 7) << 3);
        const int c = cpair * 2 + (rem >> 5), k = rem & 31;
        __builtin_amdgcn_global_load_lds(
            (const __attribute__((address_space(1))) unsigned*)(vg + (size_t)c * NPB + k),
            (__attribute__((address_space(3))) unsigned*)(vd + Lb), 16, 0, 0);
    }
}

// ---------------- flash attention: 4 blocks/CU for real TLP ------------------
// 1024 blocks x 128 thr (2 waves x 16 q-rows, QBLK=32). Block (b,half,qt):
// keys [half*2048, +2048) in 64 chunks of 32. LDS = K 16K + V 16K + P 4K = 36KB
// -> 4 blocks/CU = 8 waves/CU = 2 waves/SIMD: first config with real SIMD-level
// TLP; one wave's MFMA/VALU fills another's ds_read/barrier latency.
// Overlap: K(kc+1) staged after QK barrier, V(kc+1) after PV barrier — each
// stage is in flight across exactly one compute phase.
__global__ __launch_bounds__(128, 2) void k_attn(const ubf* __restrict__ qb, const ubf* __restrict__ kb,
                                                 const ubf* __restrict__ vt,
                                                 ubf* __restrict__ o0, ubf* __restrict__ o1,
                                                 float* __restrict__ ml) {
    __shared__ __attribute__((aligned(16))) ubf kls[32 * 256];    // 16KB
    __shared__ __attribute__((aligned(16))) ubf vls[128 * 64];    // 16KB packed V^T
    __shared__ __attribute__((aligned(16))) ubf pls[2 * 1024];    // 4KB per-wave P

    const int raw = blockIdx.x;                  // XCD swizzle: xcd = (b<<1)|half
    const int xcd = raw & 7, qt = raw >> 3;      // qt 0..127
    const int b = xcd >> 1, half = xcd & 1;

    const int wave = threadIdx.x >> 6, lane = threadIdx.x & 63;
    const int q15 = lane & 15, g = lane >> 4;
    const int swzP = (q15 & 7) << 3;

    // Q fragments (B-operand of K @ Q^T); wave owns 16 q-rows
    const ubf* qrow = qb + ((size_t)(b * NPB + qt * 32 + wave * 16 + q15)) * CD + g * 8;
    v8s qf[8];
#pragma unroll
    for (int cs = 0; cs < 8; ++cs) qf[cs] = *reinterpret_cast<const v8s*>(qrow + cs * 32);

    v4f oacc[16];
#pragma unroll
    for (int i = 0; i < 16; ++i)
#pragma unroll
        for (int r = 0; r < 4; ++r) oacc[i][r] = 0.f;
    float m_run = -3.0e38f, l_run = 0.f;

    const ubf* kgb = kb + ((size_t)(b * NPB) + half * 2048) * CD;
    const ubf* vgb = vt + (size_t)b * CD * NPB + half * 2048;
    ubf* pw = pls + wave * 1024;

    stage_k32(kgb, kls, wave, lane);
    stage_v32(vgb, vls, wave, lane);
    __syncthreads();                             // chunk 0 ready

    for (int kc = 0; kc < 64; ++kc) {
        // S' = K_chunk @ Q^T  (32 keys x 16 q)
        v4f sacc[2];
#pragma unroll
        for (int f = 0; f < 2; ++f)
#pragma unroll
            for (int r = 0; r < 4; ++r) sacc[f][r] = 0.f;
#pragma unroll
        for (int cs = 0; cs < 8; ++cs)
#pragma unroll
            for (int f = 0; f < 2; ++f) {
                const int key = 16 * f + q15;
                v8s af = *reinterpret_cast<const v8s*>(&kls[(key * CD + cs * 32 + g * 8) ^ ((key & 7) << 3)]);
                sacc[f] = __builtin_amdgcn_mfma_f32_16x16x32_bf16(af, qf[cs], sacc[f], 0, 0, 0);
            }

        __syncthreads();                         // QK reads done; V(kc) drained
        if (kc + 1 < 64)                         // K(kc+1) flies under softmax+PV
            stage_k32(kgb + (size_t)(kc + 1) * 32 * CD, kls, wave, lane);

        // online softmax with defer-rescale (THR=8)
        float mloc = -3.0e38f;
#pragma unroll
        for (int f = 0; f < 2; ++f)
#pragma unroll
            for (int r = 0; r < 4; ++r) {
                float x = sacc[f][r] * 0.0625f;
                sacc[f][r] = x;
                mloc = fmaxf(mloc, x);
            }
        mloc = fmaxf(mloc, __shfl_xor(mloc, 16));
        mloc = fmaxf(mloc, __shfl_xor(mloc, 32));
        if (!__all(mloc <= m_run + 8.0f)) {
            const float mnew  = fmaxf(m_run, mloc);
            const float alpha = __expf(m_run - mnew);
            l_run *= alpha;
#pragma unroll
            for (int i = 0; i < 16; ++i)
#pragma unroll
                for (int r = 0; r < 4; ++r) oacc[i][r] *= alpha;
            m_run = mnew;
        }
        float lloc = 0.f;
#pragma unroll
        for (int f = 0; f < 2; ++f)
#pragma unroll
            for (int r = 0; r < 4; ++r) {
                float p = __expf(sacc[f][r] - m_run);
                sacc[f][r] = p;
                lloc += p;
            }
        lloc += __shfl_xor(lloc, 16);
        lloc += __shfl_xor(lloc, 32);
        l_run += lloc;

        // P -> LDS (bf16 trunc), per-wave private, 64-elem padded rows
#pragma unroll
        for (int f = 0; f < 2; ++f) {
            unsigned u0, u1, u2, u3;
            { union { float f; unsigned u; } c; c.f = sacc[f][0]; u0 = c.u; }
            { union { float f; unsigned u; } c; c.f = sacc[f][1]; u1 = c.u; }
            { union { float f; unsigned u; } c; c.f = sacc[f][2]; u2 = c.u; }
            { union { float f; unsigned u; } c; c.f = sacc[f][3]; u3 = c.u; }
            unsigned p01 = (u0 >> 16) | (u1 & 0xFFFF0000u);
            unsigned p23 = (u2 >> 16) | (u3 & 0xFFFF0000u);
            const int e = q15 * 64 + 16 * f + 4 * g;
            *reinterpret_cast<unsigned*>(&pw[(e)     ^ swzP]) = p01;
            *reinterpret_cast<unsigned*>(&pw[(e + 2) ^ swzP]) = p23;
        }
        // O^T += V^T_chunk @ P (one MFMA per channel tile, K=32 = full chunk)
        v8s pb = *reinterpret_cast<const v8s*>(&pw[(q15 * 64 + 8 * g) ^ swzP]);
#pragma unroll
        for (int mt = 0; mt < 16; ++mt) {
            const int cp = 8 * mt + (q15 >> 1);      // (16mt+q15)>>1
            const int e  = cp * 64 + ((((q15 & 1) << 5) | (g << 3)) ^ ((q15 >> 1) << 3));
            v8s av = *reinterpret_cast<const v8s*>(&vls[e]);
            oacc[mt] = __builtin_amdgcn_mfma_f32_16x16x32_bf16(av, pb, oacc[mt], 0, 0, 0);
        }

        __syncthreads();                         // PV reads done; K(kc+1) drained
        if (kc + 1 < 64)                         // V(kc+1) flies under next QK
            stage_v32(vgb + (kc + 1) * 32, vls, wave, lane);
    }

    // epilogue: unnormalized partial O (bf16) + per-row (m, l)
    const int grow = b * NPB + qt * 32 + wave * 16 + q15;
    ubf* aor = (half ? o1 : o0) + (size_t)grow * CD;
#pragma unroll
    for (int mt = 0; mt < 16; ++mt) {
        v4u pk;
#pragma unroll
        for (int r = 0; r < 4; ++r) pk[r] = f2bf(oacc[mt][r]);
        *reinterpret_cast<v4u*>(aor + 16 * mt + 4 * g) = pk;
    }
    if (g == 0) {
        v2f d; d[0] = m_run; d[1] = l_run;
        *reinterpret_cast<v2f*>(ml + (size_t)(half * NPTS + grow) * 2) = d;
    }
}

// ---------------- fused tail: merge+mlp1 -> mlp2 -> fusion (K=512) -----------
__global__ __launch_bounds__(256) void k_tail(
    const ubf* __restrict__ o0, const ubf* __restrict__ o1, const float* __restrict__ ml,
    const float* __restrict__ xA, const ubf* __restrict__ wT,
    const float* __restrict__ mg, const float* __restrict__ mbe,
    const float* __restrict__ mm, const float* __restrict__ mv,
    const float* __restrict__ fb, const float* __restrict__ fg,
    const float* __restrict__ fbe, const float* __restrict__ fm,
    const float* __restrict__ fv, float* __restrict__ out) {
    __shared__ __attribute__((aligned(16))) ubf yls[64 * 256];   // 32KB

    const int lane = threadIdx.x & 63;
    const int w    = threadIdx.x >> 6;
    const int wr = w >> 1, wc = w & 1;
    const int q15 = lane & 15, g = lane >> 4;
    const int bm = blockIdx.x * 64;
    const int r0l = wr * 32 + q15;

    const ubf* W9  = wT + (size_t)9 * 65536;
    const ubf* W10 = wT + (size_t)10 * 65536;
    const ubf* W11 = wT + (size_t)11 * 65536;

    v4f acc[2][8];

    float a0[2], a1[2];
#pragma unroll
    for (int mi = 0; mi < 2; ++mi) {
        const int row = bm + r0l + mi * 16;
        const float m0 = ml[2 * row],          l0 = ml[2 * row + 1];
        const float m1 = ml[2 * (NPTS + row)], l1 = ml[2 * (NPTS + row) + 1];
        const float mx = fmaxf(m0, m1);
        const float w0 = __expf(m0 - mx), w1 = __expf(m1 - mx);
        const float inv = 1.0f / (w0 * l0 + w1 * l1);
        a0[mi] = w0 * inv; a1[mi] = w1 * inv;
    }
#pragma unroll
    for (int i = 0; i < 2; ++i)
#pragma unroll
        for (int j = 0; j < 8; ++j)
#pragma unroll
            for (int r = 0; r < 4; ++r) acc[i][j][r] = 0.f;
    for (int ks = 0; ks < 8; ++ks) {
        const int k0 = ks * 32 + g * 8;
        v8s afr[2], bfr[8];
#pragma unroll
        for (int mi = 0; mi < 2; ++mi) {
            const int row = bm + r0l + mi * 16;
            v8s u0 = *reinterpret_cast<const v8s*>(o0 + (size_t)row * CD + k0);
            v8s u1 = *reinterpret_cast<const v8s*>(o1 + (size_t)row * CD + k0);
            v8s t;
#pragma unroll
            for (int j = 0; j < 8; ++j)
                t[j] = (short)f2bf(a0[mi] * bf2f((ubf)u0[j]) + a1[mi] * bf2f((ubf)u1[j]));
            afr[mi] = t;
        }
#pragma unroll
        for (int ni = 0; ni < 8; ++ni)
            bfr[ni] = *reinterpret_cast<const v8s*>(W9 + (size_t)(wc * 128 + ni * 16 + q15) * 256 + k0);
#pragma unroll
        for (int mi = 0; mi < 2; ++mi)
#pragma unroll
            for (int ni = 0; ni < 8; ++ni)
                acc[mi][ni] = __builtin_amdgcn_mfma_f32_16x16x32_bf16(afr[mi], bfr[ni], acc[mi][ni], 0, 0, 0);
    }
#pragma unroll
    for (int ni = 0; ni < 8; ++ni) {
        const int col = wc * 128 + ni * 16 + q15;
        const float sc = mg[col] * rsqrtf(mv[col] + 1e-3f);
        const float tc = mbe[col] - mm[col] * sc;
#pragma unroll
        for (int mi = 0; mi < 2; ++mi)
#pragma unroll
            for (int r = 0; r < 4; ++r) {
                const int row = wr * 32 + mi * 16 + g * 4 + r;
                float z = fmaxf(acc[mi][ni][r] * sc + tc, 0.f);
                yls[row * 256 + (col ^ ((row & 7) << 3))] = f2bf(z);
            }
    }
    __syncthreads();

#pragma unroll
    for (int i = 0; i < 2; ++i)
#pragma unroll
        for (int j = 0; j < 8; ++j)
#pragma unroll
            for (int r = 0; r < 4; ++r) acc[i][j][r] = 0.f;
    for (int ks = 0; ks < 8; ++ks) {
        const int k0 = ks * 32 + g * 8;
        v8s afr[2], bfr[8];
#pragma unroll
        for (int mi = 0; mi < 2; ++mi) {
            const int row = r0l + mi * 16;
            afr[mi] = *reinterpret_cast<const v8s*>(&yls[row * 256 + (k0 ^ ((row & 7) << 3))]);
        }
#pragma unroll
        for (int ni = 0; ni < 8; ++ni)
            bfr[ni] = *reinterpret_cast<const v8s*>(W10 + (size_t)(wc * 128 + ni * 16 + q15) * 256 + k0);
#pragma unroll
        for (int mi = 0; mi < 2; ++mi)
#pragma unroll
            for (int ni = 0; ni < 8; ++ni)
                acc[mi][ni] = __builtin_amdgcn_mfma_f32_16x16x32_bf16(afr[mi], bfr[ni], acc[mi][ni], 0, 0, 0);
    }
    __syncthreads();
#pragma unroll
    for (int ni = 0; ni < 8; ++ni) {
        const int col = wc * 128 + ni * 16 + q15;
        const float sc = mg[256 + col] * rsqrtf(mv[256 + col] + 1e-3f);
        const float tc = mbe[256 + col] - mm[256 + col] * sc;
#pragma unroll
        for (int mi = 0; mi < 2; ++mi)
#pragma unroll
            for (int r = 0; r < 4; ++r) {
                const int row = wr * 32 + mi * 16 + g * 4 + r;
                float z = fmaxf(acc[mi][ni][r] * sc + tc, 0.f);
                yls[row * 256 + (col ^ ((row & 7) << 3))] = f2bf(z);
            }
    }
    __syncthreads();

#pragma unroll
    for (int i = 0; i < 2; ++i)
#pragma unroll
        for (int j = 0; j < 8; ++j)
#pragma unroll
            for (int r = 0; r < 4; ++r) acc[i][j][r] = 0.f;
    for (int ks = 0; ks < 16; ++ks) {
        const int k0 = ks * 32 + g * 8;
        v8s afr[2], bfr[8];
#pragma unroll
        for (int mi = 0; mi < 2; ++mi) {
            if (k0 < 256) {
                const float* ap = xA + (size_t)(bm + r0l + mi * 16) * CD + k0;
                v4f a = *reinterpret_cast<const v4f*>(ap);
                v4f b = *reinterpret_cast<const v4f*>(ap + 4);
                v8s t;
#pragma unroll
                for (int j = 0; j < 4; ++j) { t[j] = (short)f2bf(a[j]); t[j + 4] = (short)f2bf(b[j]); }
                afr[mi] = t;
            } else {
                const int row = r0l + mi * 16, kk = k0 - 256;
                afr[mi] = *reinterpret_cast<const v8s*>(&yls[row * 256 + (kk ^ ((row & 7) << 3))]);
            }
        }
#pragma unroll
        for (int ni = 0; ni < 8; ++ni)
            bfr[ni] = *reinterpret_cast<const v8s*>(W11 + (size_t)(wc * 128 + ni * 16 + q15) * 512 + k0);
#pragma unroll
        for (int mi = 0; mi < 2; ++mi)
#pragma unroll
            for (int ni = 0; ni < 8; ++ni)
                acc[mi][ni] = __builtin_amdgcn_mfma_f32_16x16x32_bf16(afr[mi], bfr[ni], acc[mi][ni], 0, 0, 0);
    }
#pragma unroll
    for (int ni = 0; ni < 8; ++ni) {
        const int col = wc * 128 + ni * 16 + q15;
        const float sc = fg[col] * rsqrtf(fv[col] + 1e-3f);
        const float tc = fbe[col] - fm[col] * sc;
        const float bia = fb[col];
#pragma unroll
        for (int mi = 0; mi < 2; ++mi)
#pragma unroll
            for (int r = 0; r < 4; ++r) {
                const int row = bm + wr * 32 + mi * 16 + g * 4 + r;
                float z = fmaxf((acc[mi][ni][r] + bia) * sc + tc, 0.f);
                out[(size_t)row * CD + col] = z;
            }
    }
}

// ---------------- launcher ---------------------------------------------------
extern "C" void kernel_launch(void* const* d_in, const int* in_sizes, int n_in,
                              void* d_out, int out_size, void* d_ws, size_t ws_size,
                              hipStream_t stream) {
    const float* f_low   = (const float*)d_in[0];
    const float* f_high  = (const float*)d_in[1];
    const float* bott_W  = (const float*)d_in[2];
    const float* bott_b  = (const float*)d_in[3];
    const float* bott_g  = (const float*)d_in[4];
    const float* bott_be = (const float*)d_in[5];
    const float* bott_m  = (const float*)d_in[6];
    const float* bott_v  = (const float*)d_in[7];
    const float* qkv_W   = (const float*)d_in[8];
    const float* qkv_g   = (const float*)d_in[9];
    const float* qkv_be  = (const float*)d_in[10];
    const float* qkv_m   = (const float*)d_in[11];
    const float* qkv_v   = (const float*)d_in[12];
    const float* mlp_W   = (const float*)d_in[13];
    const float* mlp_g   = (const float*)d_in[14];
    const float* mlp_be  = (const float*)d_in[15];
    const float* mlp_m   = (const float*)d_in[16];
    const float* mlp_v   = (const float*)d_in[17];
    const float* fus_W   = (const float*)d_in[18];
    const float* fus_b   = (const float*)d_in[19];
    const float* fus_g   = (const float*)d_in[20];
    const float* fus_be  = (const float*)d_in[21];
    const float* fus_m   = (const float*)d_in[22];
    const float* fus_v   = (const float*)d_in[23];
    (void)in_sizes; (void)n_in; (void)out_size; (void)ws_size;

    char* ws = (char*)d_ws;
    const size_t MB = 1024 * 1024;
    float* xA = (float*)(ws);                       // 16.8 MB residual stream
    ubf*   o0 = (ubf*)  (ws + 17 * MB);             // 8.4 MB attn half0 partial
    ubf*   qB = (ubf*)  (ws + 26 * MB);             // 8.4 MB Q
    ubf*   kB = (ubf*)  (ws + 35 * MB);             // 8.4 MB K
    ubf*   vT = (ubf*)  (ws + 44 * MB);             // 8.4 MB V^T [B][C][n]
    ubf*   wT = (ubf*)  (ws + 53 * MB);             // 1.7 MB, 12 transposed weights
    ubf*   o1 = (ubf*)  (ws + 56 * MB);             // 8.4 MB attn half1 partial
    float* ml = (float*)(ws + 65 * MB);             // 512 KB (m,l) x 2 halves

    k_pre<<<dim3(4096 + 1536), dim3(256), 0, stream>>>(f_low, xA,
                                                       bott_W, qkv_W, mlp_W, fus_W, wT);

    k_conv1<<<dim3(256), dim3(256), 0, stream>>>(xA, wT,
                                                 bott_b, bott_g, bott_be, bott_m, bott_v);

    k_qkv<<<dim3(128, 6), dim3(256), 0, stream>>>(xA, f_high, wT + (size_t)6 * 65536,
                                                  qkv_g, qkv_be, qkv_m, qkv_v, qB, kB, vT);

    k_attn<<<dim3(1024), dim3(128), 0, stream>>>(qB, kB, vT, o0, o1, ml);

    k_tail<<<dim3(256), dim3(256), 0, stream>>>(o0, o1, ml, xA, wT,
                                                mlp_g, mlp_be, mlp_m, mlp_v,
                                                fus_b, fus_g, fus_be, fus_m, fus_v,
                                                (float*)d_out);
}

// Round 15
// 287.142 us; speedup vs baseline: 1.2327x; 1.0640x over previous
//
#include <hip/hip_runtime.h>
#include <cstdint>
#include <cstddef>

typedef float v4f __attribute__((ext_vector_type(4)));
typedef float v2f __attribute__((ext_vector_type(2)));
typedef float v16f __attribute__((ext_vector_type(16)));
typedef short v8s __attribute__((ext_vector_type(8)));
typedef unsigned short v4u __attribute__((ext_vector_type(4)));

typedef unsigned short ubf;   // raw bf16 bits

#define NPTS 16384
#define CD   256
#define NBAT 4
#define NPB  4096

__device__ __forceinline__ float bf2f(ubf u) {
    union { unsigned u; float f; } c; c.u = ((unsigned)u) << 16; return c.f;
}
__device__ __forceinline__ ubf f2bf(float f) {
    union { float f; unsigned u; } c; c.f = f;
    unsigned u = c.u;
    u += 0x7fffu + ((u >> 16) & 1u);           // round-nearest-even
    return (ubf)(u >> 16);
}

// -------- fused pre-pass: weight transpose (blocks >= 4096) + point attention
__global__ __launch_bounds__(256) void k_pre(
    const float* __restrict__ low, float* __restrict__ xout,
    const float* __restrict__ bott, const float* __restrict__ qkv,
    const float* __restrict__ mlp, const float* __restrict__ fus,
    ubf* __restrict__ wt) {
    const int bid = blockIdx.x;
    if (bid < 4096) {
        // ---- Point_Attentation ----
        const int lane = threadIdx.x & 63;
        const int row  = bid * 4 + (threadIdx.x >> 6);
        const float* p = low + (size_t)row * CD + lane * 4;
        v4f v = *reinterpret_cast<const v4f*>(p);
        float d[4];
        float s = v[0] + v[1] + v[2] + v[3];
#pragma unroll
        for (int o = 32; o >= 1; o >>= 1) s += __shfl_xor(s, o);
        const float mean = s * (1.0f / 256.0f);
        float ss = 0.f;
#pragma unroll
        for (int i = 0; i < 4; ++i) { d[i] = v[i] - mean; ss += d[i] * d[i]; }
#pragma unroll
        for (int o = 32; o >= 1; o >>= 1) ss += __shfl_xor(ss, o);
        const float var = ss * (1.0f / 4095.0f);    // reference: /(n-1), n=4096
        const float dn  = 1.0f / (4.0f * (var + 1e-5f));
        v4f o;
#pragma unroll
        for (int i = 0; i < 4; ++i) {
            const float e   = d[i] * d[i] * dn + 0.5f;
            const float sig = 1.0f / (1.0f + __expf(-e));
            o[i] = v[i] * (1.0f + sig);
        }
        *reinterpret_cast<v4f*>(xout + (size_t)row * CD + lane * 4) = o;
        return;
    }
    // ---- weight transpose+convert: W[K][256] f32 -> WT[256][K] bf16 ----
    const int bid2 = bid - 4096;
    const int z = bid2 >> 7, r = bid2 & 127;
    const float* src; int K; size_t doff;
    if (z < 6)       { src = bott + (size_t)z * 65536;       K = 256; doff = (size_t)z * 65536; }
    else if (z < 9)  { src = qkv  + (size_t)(z - 6) * 65536; K = 256; doff = (size_t)z * 65536; }
    else if (z < 11) { src = mlp  + (size_t)(z - 9) * 65536; K = 256; doff = (size_t)z * 65536; }
    else             { src = fus;                            K = 512; doff = (size_t)11 * 65536; }
    const int kt = (r >> 3) * 32, nt = (r & 7) * 32;
    if (kt >= K) return;
    __shared__ ubf tile[32][33];
    const int tx = threadIdx.x & 31, ty = threadIdx.x >> 5;   // 32 x 8
#pragma unroll
    for (int i = 0; i < 4; ++i)
        tile[ty * 4 + i][tx] = f2bf(src[(size_t)(kt + ty * 4 + i) * 256 + nt + tx]);
    __syncthreads();
    ubf* dst = wt + doff;
#pragma unroll
    for (int i = 0; i < 4; ++i)
        dst[(size_t)(nt + ty * 4 + i) * K + kt + tx] = tile[tx][ty * 4 + i];
}

// ---------------- fused conv1: 3 bottlenecks (6 GEMMs) in one dispatch -------
__global__ __launch_bounds__(256) void k_conv1(
    float* __restrict__ xA, const ubf* __restrict__ wT,
    const float* __restrict__ bb, const float* __restrict__ bg,
    const float* __restrict__ bbe, const float* __restrict__ bm_,
    const float* __restrict__ bv) {
    __shared__ __attribute__((aligned(16))) float xls[64 * 256];  // 64KB
    __shared__ __attribute__((aligned(16))) ubf   yls[64 * 256];  // 32KB

    const int lane = threadIdx.x & 63;
    const int w    = threadIdx.x >> 6;
    const int wr = w >> 1, wc = w & 1;
    const int q15 = lane & 15, g = lane >> 4;
    const int bm = blockIdx.x * 64;

    {
        float* xsrcb = xA + (size_t)bm * 256;
#pragma unroll
        for (int it = 0; it < 16; ++it) {
            const int L4 = (it * 256 + w * 64) * 4;      // wave-uniform f32 base
            const int Ll = L4 + lane * 4;
            const int row = Ll >> 8, col = (Ll & 255) ^ ((row & 7) << 3);
            __builtin_amdgcn_global_load_lds(
                (const __attribute__((address_space(1))) unsigned*)(xsrcb + row * 256 + col),
                (__attribute__((address_space(3))) unsigned*)(xls + L4), 16, 0, 0);
        }
    }
    __syncthreads();

    const int r0l = wr * 32 + q15;
#pragma unroll 1
    for (int s = 0; s < 3; ++s) {
        const ubf* W0 = wT + (size_t)(2 * s) * 65536;
        const ubf* W1 = wT + (size_t)(2 * s + 1) * 65536;

        v4f acc[2][8];
#pragma unroll
        for (int i = 0; i < 2; ++i)
#pragma unroll
            for (int j = 0; j < 8; ++j)
#pragma unroll
                for (int r = 0; r < 4; ++r) acc[i][j][r] = 0.f;
        for (int ks = 0; ks < 8; ++ks) {
            const int k0 = ks * 32 + g * 8;
            v8s afr[2], bfr[8];
#pragma unroll
            for (int mi = 0; mi < 2; ++mi) {
                const int row = r0l + mi * 16;
                const float* ap = &xls[row * 256 + (k0 ^ ((row & 7) << 3))];
                v4f a = *reinterpret_cast<const v4f*>(ap);
                v4f b = *reinterpret_cast<const v4f*>(ap + 4);
                v8s t;
#pragma unroll
                for (int j = 0; j < 4; ++j) { t[j] = (short)f2bf(a[j]); t[j + 4] = (short)f2bf(b[j]); }
                afr[mi] = t;
            }
#pragma unroll
            for (int ni = 0; ni < 8; ++ni)
                bfr[ni] = *reinterpret_cast<const v8s*>(W0 + (size_t)(wc * 128 + ni * 16 + q15) * 256 + k0);
#pragma unroll
            for (int mi = 0; mi < 2; ++mi)
#pragma unroll
                for (int ni = 0; ni < 8; ++ni)
                    acc[mi][ni] = __builtin_amdgcn_mfma_f32_16x16x32_bf16(afr[mi], bfr[ni], acc[mi][ni], 0, 0, 0);
        }
#pragma unroll
        for (int ni = 0; ni < 8; ++ni) {
            const int col = wc * 128 + ni * 16 + q15;
            const float sc  = bg[2 * s * 256 + col] * rsqrtf(bv[2 * s * 256 + col] + 1e-3f);
            const float tc  = bbe[2 * s * 256 + col] - bm_[2 * s * 256 + col] * sc;
            const float bia = bb[2 * s * 256 + col];
#pragma unroll
            for (int mi = 0; mi < 2; ++mi)
#pragma unroll
                for (int r = 0; r < 4; ++r) {
                    const int row = wr * 32 + mi * 16 + g * 4 + r;
                    float z = fmaxf((acc[mi][ni][r] + bia) * sc + tc, 0.f);
                    yls[row * 256 + (col ^ ((row & 7) << 3))] = f2bf(z);
                }
        }
        __syncthreads();

#pragma unroll
        for (int i = 0; i < 2; ++i)
#pragma unroll
            for (int j = 0; j < 8; ++j)
#pragma unroll
                for (int r = 0; r < 4; ++r) acc[i][j][r] = 0.f;
        for (int ks = 0; ks < 8; ++ks) {
            const int k0 = ks * 32 + g * 8;
            v8s afr[2], bfr[8];
#pragma unroll
            for (int mi = 0; mi < 2; ++mi) {
                const int row = r0l + mi * 16;
                afr[mi] = *reinterpret_cast<const v8s*>(&yls[row * 256 + (k0 ^ ((row & 7) << 3))]);
            }
#pragma unroll
            for (int ni = 0; ni < 8; ++ni)
                bfr[ni] = *reinterpret_cast<const v8s*>(W1 + (size_t)(wc * 128 + ni * 16 + q15) * 256 + k0);
#pragma unroll
            for (int mi = 0; mi < 2; ++mi)
#pragma unroll
                for (int ni = 0; ni < 8; ++ni)
                    acc[mi][ni] = __builtin_amdgcn_mfma_f32_16x16x32_bf16(afr[mi], bfr[ni], acc[mi][ni], 0, 0, 0);
        }
#pragma unroll
        for (int ni = 0; ni < 8; ++ni) {
            const int col = wc * 128 + ni * 16 + q15;
            const int c1 = (2 * s + 1) * 256 + col;
            const float sc  = bg[c1] * rsqrtf(bv[c1] + 1e-3f);
            const float tc  = bbe[c1] - bm_[c1] * sc;
            const float bia = bb[c1];
#pragma unroll
            for (int mi = 0; mi < 2; ++mi)
#pragma unroll
                for (int r = 0; r < 4; ++r) {
                    const int row = wr * 32 + mi * 16 + g * 4 + r;
                    float z = fmaxf((acc[mi][ni][r] + bia) * sc + tc, 0.f);
                    xls[row * 256 + (col ^ ((row & 7) << 3))] += z;
                }
        }
        __syncthreads();
    }

    {
        float* xdstb = xA + (size_t)bm * 256;
#pragma unroll
        for (int it = 0; it < 16; ++it) {
            const int Ll = (it * 256 + threadIdx.x) * 4;
            const int row = Ll >> 8, cl = Ll & 255;
            const int gcol = cl ^ ((row & 7) << 3);
            *reinterpret_cast<v4f*>(xdstb + row * 256 + gcol) =
                *reinterpret_cast<const v4f*>(xls + Ll);
        }
    }
}

// ---------------- fused QKV projection: one dispatch, 768 blocks -------------
// V written CHUNK-MAJOR: vT[b][chunk=key>>5][c][key&31] (16KB contiguous per
// 32-key chunk) so k_attn can stage it into a stride-40 LDS layout.
__global__ __launch_bounds__(256) void k_qkv(
    const float* __restrict__ xA, const float* __restrict__ fh,
    const ubf* __restrict__ wTq,
    const float* __restrict__ qg, const float* __restrict__ qbe,
    const float* __restrict__ qm, const float* __restrict__ qv,
    ubf* __restrict__ qB, ubf* __restrict__ kB, ubf* __restrict__ vT) {
    const int m = blockIdx.y >> 1;               // 0=q, 1=k, 2=v
    const float* Af = (m == 0) ? xA : fh;
    const ubf* WT = wTq + m * 65536;
    const float* gamma = qg + m * 256;
    const float* beta  = qbe + m * 256;
    const float* bmean = qm + m * 256;
    const float* bvar  = qv + m * 256;

    const int lane = threadIdx.x & 63;
    const int w    = threadIdx.x >> 6;
    const int wr = w >> 1, wc = w & 1;
    const int q15 = lane & 15, g = lane >> 4;
    const int bm = blockIdx.x * 128, bn = (blockIdx.y & 1) * 128;
    const int r0 = bm + wr * 64 + q15;
    const int c0 = bn + wc * 64 + q15;

    v4f acc[4][4];
#pragma unroll
    for (int i = 0; i < 4; ++i)
#pragma unroll
        for (int j = 0; j < 4; ++j)
#pragma unroll
            for (int r = 0; r < 4; ++r) acc[i][j][r] = 0.f;

    for (int ks = 0; ks < 8; ++ks) {
        const int k0 = ks * 32 + g * 8;
        v8s afr[4], bfr[4];
#pragma unroll
        for (int mi = 0; mi < 4; ++mi) {
            const float* ap = Af + (size_t)(r0 + mi * 16) * CD + k0;
            v4f a = *reinterpret_cast<const v4f*>(ap);
            v4f b = *reinterpret_cast<const v4f*>(ap + 4);
            v8s t;
#pragma unroll
            for (int j = 0; j < 4; ++j) { t[j] = (short)f2bf(a[j]); t[j + 4] = (short)f2bf(b[j]); }
            afr[mi] = t;
        }
#pragma unroll
        for (int ni = 0; ni < 4; ++ni)
            bfr[ni] = *reinterpret_cast<const v8s*>(WT + (size_t)(c0 + ni * 16) * 256 + k0);
#pragma unroll
        for (int mi = 0; mi < 4; ++mi)
#pragma unroll
            for (int ni = 0; ni < 4; ++ni)
                acc[mi][ni] = __builtin_amdgcn_mfma_f32_16x16x32_bf16(afr[mi], bfr[ni], acc[mi][ni], 0, 0, 0);
    }

    ubf* outb = (m == 0) ? qB : kB;
#pragma unroll
    for (int ni = 0; ni < 4; ++ni) {
        const int col = c0 + ni * 16;
        const float sc = gamma[col] * rsqrtf(bvar[col] + 1e-3f);
        const float tc = beta[col] - bmean[col] * sc;
#pragma unroll
        for (int mi = 0; mi < 4; ++mi) {
            if (m == 2) {
                const int row0 = bm + wr * 64 + mi * 16 + g * 4;
                v4u pk;
#pragma unroll
                for (int r = 0; r < 4; ++r) pk[r] = f2bf(acc[mi][ni][r] * sc + tc);
                const int bb = row0 >> 12, key = row0 & 4095;
                const int ch = key >> 5, kin = key & 31;
                *reinterpret_cast<v4u*>(vT + (size_t)bb * (CD * NPB)
                                           + (size_t)ch * (CD * 32) + col * 32 + kin) = pk;
            } else {
#pragma unroll
                for (int r = 0; r < 4; ++r) {
                    const int row = bm + wr * 64 + mi * 16 + g * 4 + r;
                    outb[(size_t)row * CD + col] = f2bf(acc[mi][ni][r] * sc + tc);
                }
            }
        }
    }
}

// ---- async stages (128-thread block, 2 waves) -------------------------------
// K chunk [32][256] (16KB), row col-swizzle ^((key&7)<<3) on the global source.
__device__ __forceinline__ void stage_k32(const ubf* __restrict__ kg,
                                          ubf* kd, int wave, int lane) {
#pragma unroll
    for (int it = 0; it < 8; ++it) {
        const int Lb = it * 1024 + wave * 512;
        const int L  = Lb + lane * 8;
        const int key = L >> 8, c8 = (L & 255) ^ ((key & 7) << 3);
        __builtin_amdgcn_global_load_lds(
            (const __attribute__((address_space(1))) unsigned*)(kg + key * CD + c8),
            (__attribute__((address_space(3))) unsigned*)(kd + Lb), 16, 0, 0);
    }
}
// V^T chunk -> stride-40 rows: vls[c*40 + k], k 0..31 data, 32..39 pad.
// Source is the chunk-major global block (c*32 + k); pad slots load base.
__device__ __forceinline__ void stage_v40(const ubf* __restrict__ vchunk,
                                          ubf* vd, int wave, int lane) {
#pragma unroll
    for (int it = 0; it < 10; ++it) {
        const int e0b = wave * 5120 + it * 512;      // wave-uniform elem base
        const int e0  = e0b + lane * 8;
        const int c   = e0 / 40;
        const int k0  = e0 - c * 40;                 // 0,8,16,24,32
        const ubf* src = (k0 < 32) ? (vchunk + c * 32 + k0) : vchunk;
        __builtin_amdgcn_global_load_lds(
            (const __attribute__((address_space(1))) unsigned*)src,
            (__attribute__((address_space(3))) unsigned*)(vd + e0b), 16, 0, 0);
    }
}

// ---------------- flash attention: 32x32x16 MFMA (half LDS traffic/FLOP) -----
// 512 blocks x 128 thr (2 waves x 32 q-rows, QBLK=64). Block (b,half,qt):
// keys [half*2048,+2048) in 64 chunks of 32. LDS = K 16K + V 20K + P 5K = 41KB.
// QK: S[32k][32q] = K@Q^T (A=K from LDS, B=Q regs), 16 MFMAs of 32x32x16.
// C/D layout (m74/m101): col=lane&31(=q), row=(reg&3)+8(reg>>2)+4(lane>>5).
// Softmax: 16 regs + one shfl_xor(32). PV: O[c][q] += V^T@P, 16 MFMAs.
__global__ __launch_bounds__(128, 1) void k_attn(const ubf* __restrict__ qb, const ubf* __restrict__ kb,
                                                 const ubf* __restrict__ vt,
                                                 ubf* __restrict__ o0, ubf* __restrict__ o1,
                                                 float* __restrict__ ml) {
    __shared__ __attribute__((aligned(16))) ubf kls[32 * 256];    // 16KB
    __shared__ __attribute__((aligned(16))) ubf vls[256 * 40];    // 20KB stride-40
    __shared__ __attribute__((aligned(16))) ubf pls[2 * 32 * 40]; // 5KB per-wave P

    const int raw = blockIdx.x;                  // XCD swizzle: xcd = (b<<1)|half
    const int xcd = raw & 7, qt = raw >> 3;      // qt 0..63
    const int b = xcd >> 1, half = xcd & 1;

    const int wave = threadIdx.x >> 6, lane = threadIdx.x & 63;
    const int q31 = lane & 31, h = lane >> 5;

    // Q fragments: qf[ks] = Q[q31][ks*16 + h*8 .. +8]  (B-operand of K@Q^T)
    const ubf* qrow = qb + ((size_t)(b * NPB + qt * 64 + wave * 32 + q31)) * CD + h * 8;
    v8s qf[16];
#pragma unroll
    for (int ks = 0; ks < 16; ++ks) qf[ks] = *reinterpret_cast<const v8s*>(qrow + ks * 16);

    v16f oacc[8];
#pragma unroll
    for (int t = 0; t < 8; ++t)
#pragma unroll
        for (int r = 0; r < 16; ++r) oacc[t][r] = 0.f;
    float m_run = -3.0e38f, l_run = 0.f;

    const ubf* kgb = kb + ((size_t)(b * NPB) + half * 2048) * CD;
    const ubf* vgb = vt + (size_t)b * (CD * NPB) + (size_t)(half * 64) * (CD * 32);
    ubf* pw = pls + wave * (32 * 40);

    stage_k32(kgb, kls, wave, lane);
    stage_v40(vgb, vls, wave, lane);
    __syncthreads();                             // chunk 0 ready

    for (int kc = 0; kc < 64; ++kc) {
        // S' = K_chunk @ Q^T : A-frag lane reads K[key=q31][ks*16 + h*8 ..]
        v16f sacc;
#pragma unroll
        for (int r = 0; r < 16; ++r) sacc[r] = 0.f;
#pragma unroll
        for (int ks = 0; ks < 16; ++ks) {
            v8s af = *reinterpret_cast<const v8s*>(
                &kls[q31 * 256 + ((ks * 16 + h * 8) ^ ((q31 & 7) << 3))]);
            sacc = __builtin_amdgcn_mfma_f32_32x32x16_bf16(af, qf[ks], sacc, 0, 0, 0);
        }

        __syncthreads();                         // kls reads done; V(kc) drained
        if (kc + 1 < 64)                         // K(kc+1) flies under softmax+PV
            stage_k32(kgb + (size_t)(kc + 1) * 32 * CD, kls, wave, lane);

        // online softmax with defer-rescale (THR=8); lane owns q=q31, 16 keys
        float mloc = -3.0e38f;
#pragma unroll
        for (int r = 0; r < 16; ++r) {
            float x = sacc[r] * 0.0625f;
            sacc[r] = x;
            mloc = fmaxf(mloc, x);
        }
        mloc = fmaxf(mloc, __shfl_xor(mloc, 32));
        if (!__all(mloc <= m_run + 8.0f)) {
            const float mnew  = fmaxf(m_run, mloc);
            const float alpha = __expf(m_run - mnew);
            l_run *= alpha;
#pragma unroll
            for (int t = 0; t < 8; ++t)
#pragma unroll
                for (int r = 0; r < 16; ++r) oacc[t][r] *= alpha;
            m_run = mnew;
        }
        float lloc = 0.f;
#pragma unroll
        for (int r = 0; r < 16; ++r) {
            float p = __expf(sacc[r] - m_run);
            sacc[r] = p;
            lloc += p;
        }
        lloc += __shfl_xor(lloc, 32);
        l_run += lloc;

        // P -> LDS (bf16 trunc): reg 4G+r holds key = r + 8G + 4h for q31
#pragma unroll
        for (int G = 0; G < 4; ++G) {
            unsigned u0, u1, u2, u3;
            { union { float f; unsigned u; } c; c.f = sacc[4 * G + 0]; u0 = c.u; }
            { union { float f; unsigned u; } c; c.f = sacc[4 * G + 1]; u1 = c.u; }
            { union { float f; unsigned u; } c; c.f = sacc[4 * G + 2]; u2 = c.u; }
            { union { float f; unsigned u; } c; c.f = sacc[4 * G + 3]; u3 = c.u; }
            unsigned p01 = (u0 >> 16) | (u1 & 0xFFFF0000u);
            unsigned p23 = (u2 >> 16) | (u3 & 0xFFFF0000u);
            const int e = q31 * 40 + 8 * G + 4 * h;
            *reinterpret_cast<unsigned*>(&pw[e])     = p01;
            *reinterpret_cast<unsigned*>(&pw[e + 2]) = p23;
        }
        // O[c][q] += V^T_chunk @ P : B-frag = P[kb + h*8 ..][q31]
        v8s pb0 = *reinterpret_cast<const v8s*>(&pw[q31 * 40 + 0  + 8 * h]);
        v8s pb1 = *reinterpret_cast<const v8s*>(&pw[q31 * 40 + 16 + 8 * h]);
#pragma unroll
        for (int t = 0; t < 8; ++t) {
            const int crow = (t * 32 + q31) * 40;
            v8s av0 = *reinterpret_cast<const v8s*>(&vls[crow + 0  + 8 * h]);
            oacc[t] = __builtin_amdgcn_mfma_f32_32x32x16_bf16(av0, pb0, oacc[t], 0, 0, 0);
            v8s av1 = *reinterpret_cast<const v8s*>(&vls[crow + 16 + 8 * h]);
            oacc[t] = __builtin_amdgcn_mfma_f32_32x32x16_bf16(av1, pb1, oacc[t], 0, 0, 0);
        }

        __syncthreads();                         // vls reads done; K(kc+1) drained
        if (kc + 1 < 64)                         // V(kc+1) flies under next QK
            stage_v40(vgb + (size_t)(kc + 1) * (CD * 32), vls, wave, lane);
    }

    // epilogue: unnormalized partial O (bf16) + per-row (m, l)
    const int grow = b * NPB + qt * 64 + wave * 32 + q31;
    ubf* aor = (half ? o1 : o0) + (size_t)grow * CD;
#pragma unroll
    for (int t = 0; t < 8; ++t)
#pragma unroll
        for (int G = 0; G < 4; ++G) {
            v4u pk;
#pragma unroll
            for (int r = 0; r < 4; ++r) pk[r] = f2bf(oacc[t][4 * G + r]);
            *reinterpret_cast<v4u*>(aor + t * 32 + 8 * G + 4 * h) = pk;
        }
    if (h == 0) {
        v2f d; d[0] = m_run; d[1] = l_run;
        *reinterpret_cast<v2f*>(ml + (size_t)(half * NPTS + grow) * 2) = d;
    }
}

// ---------------- fused tail: merge+mlp1 -> mlp2 -> fusion (K=512) -----------
__global__ __launch_bounds__(256) void k_tail(
    const ubf* __restrict__ o0, const ubf* __restrict__ o1, const float* __restrict__ ml,
    const float* __restrict__ xA, const ubf* __restrict__ wT,
    const float* __restrict__ mg, const float* __restrict__ mbe,
    const float* __restrict__ mm, const float* __restrict__ mv,
    const float* __restrict__ fb, const float* __restrict__ fg,
    const float* __restrict__ fbe, const float* __restrict__ fm,
    const float* __restrict__ fv, float* __restrict__ out) {
    __shared__ __attribute__((aligned(16))) ubf yls[64 * 256];   // 32KB

    const int lane = threadIdx.x & 63;
    const int w    = threadIdx.x >> 6;
    const int wr = w >> 1, wc = w & 1;
    const int q15 = lane & 15, g = lane >> 4;
    const int bm = blockIdx.x * 64;
    const int r0l = wr * 32 + q15;

    const ubf* W9  = wT + (size_t)9 * 65536;
    const ubf* W10 = wT + (size_t)10 * 65536;
    const ubf* W11 = wT + (size_t)11 * 65536;

    v4f acc[2][8];

    float a0[2], a1[2];
#pragma unroll
    for (int mi = 0; mi < 2; ++mi) {
        const int row = bm + r0l + mi * 16;
        const float m0 = ml[2 * row],          l0 = ml[2 * row + 1];
        const float m1 = ml[2 * (NPTS + row)], l1 = ml[2 * (NPTS + row) + 1];
        const float mx = fmaxf(m0, m1);
        const float w0 = __expf(m0 - mx), w1 = __expf(m1 - mx);
        const float inv = 1.0f / (w0 * l0 + w1 * l1);
        a0[mi] = w0 * inv; a1[mi] = w1 * inv;
    }
#pragma unroll
    for (int i = 0; i < 2; ++i)
#pragma unroll
        for (int j = 0; j < 8; ++j)
#pragma unroll
            for (int r = 0; r < 4; ++r) acc[i][j][r] = 0.f;
    for (int ks = 0; ks < 8; ++ks) {
        const int k0 = ks * 32 + g * 8;
        v8s afr[2], bfr[8];
#pragma unroll
        for (int mi = 0; mi < 2; ++mi) {
            const int row = bm + r0l + mi * 16;
            v8s u0 = *reinterpret_cast<const v8s*>(o0 + (size_t)row * CD + k0);
            v8s u1 = *reinterpret_cast<const v8s*>(o1 + (size_t)row * CD + k0);
            v8s t;
#pragma unroll
            for (int j = 0; j < 8; ++j)
                t[j] = (short)f2bf(a0[mi] * bf2f((ubf)u0[j]) + a1[mi] * bf2f((ubf)u1[j]));
            afr[mi] = t;
        }
#pragma unroll
        for (int ni = 0; ni < 8; ++ni)
            bfr[ni] = *reinterpret_cast<const v8s*>(W9 + (size_t)(wc * 128 + ni * 16 + q15) * 256 + k0);
#pragma unroll
        for (int mi = 0; mi < 2; ++mi)
#pragma unroll
            for (int ni = 0; ni < 8; ++ni)
                acc[mi][ni] = __builtin_amdgcn_mfma_f32_16x16x32_bf16(afr[mi], bfr[ni], acc[mi][ni], 0, 0, 0);
    }
#pragma unroll
    for (int ni = 0; ni < 8; ++ni) {
        const int col = wc * 128 + ni * 16 + q15;
        const float sc = mg[col] * rsqrtf(mv[col] + 1e-3f);
        const float tc = mbe[col] - mm[col] * sc;
#pragma unroll
        for (int mi = 0; mi < 2; ++mi)
#pragma unroll
            for (int r = 0; r < 4; ++r) {
                const int row = wr * 32 + mi * 16 + g * 4 + r;
                float z = fmaxf(acc[mi][ni][r] * sc + tc, 0.f);
                yls[row * 256 + (col ^ ((row & 7) << 3))] = f2bf(z);
            }
    }
    __syncthreads();

#pragma unroll
    for (int i = 0; i < 2; ++i)
#pragma unroll
        for (int j = 0; j < 8; ++j)
#pragma unroll
            for (int r = 0; r < 4; ++r) acc[i][j][r] = 0.f;
    for (int ks = 0; ks < 8; ++ks) {
        const int k0 = ks * 32 + g * 8;
        v8s afr[2], bfr[8];
#pragma unroll
        for (int mi = 0; mi < 2; ++mi) {
            const int row = r0l + mi * 16;
            afr[mi] = *reinterpret_cast<const v8s*>(&yls[row * 256 + (k0 ^ ((row & 7) << 3))]);
        }
#pragma unroll
        for (int ni = 0; ni < 8; ++ni)
            bfr[ni] = *reinterpret_cast<const v8s*>(W10 + (size_t)(wc * 128 + ni * 16 + q15) * 256 + k0);
#pragma unroll
        for (int mi = 0; mi < 2; ++mi)
#pragma unroll
            for (int ni = 0; ni < 8; ++ni)
                acc[mi][ni] = __builtin_amdgcn_mfma_f32_16x16x32_bf16(afr[mi], bfr[ni], acc[mi][ni], 0, 0, 0);
    }
    __syncthreads();
#pragma unroll
    for (int ni = 0; ni < 8; ++ni) {
        const int col = wc * 128 + ni * 16 + q15;
        const float sc = mg[256 + col] * rsqrtf(mv[256 + col] + 1e-3f);
        const float tc = mbe[256 + col] - mm[256 + col] * sc;
#pragma unroll
        for (int mi = 0; mi < 2; ++mi)
#pragma unroll
            for (int r = 0; r < 4; ++r) {
                const int row = wr * 32 + mi * 16 + g * 4 + r;
                float z = fmaxf(acc[mi][ni][r] * sc + tc, 0.f);
                yls[row * 256 + (col ^ ((row & 7) << 3))] = f2bf(z);
            }
    }
    __syncthreads();

#pragma unroll
    for (int i = 0; i < 2; ++i)
#pragma unroll
        for (int j = 0; j < 8; ++j)
#pragma unroll
            for (int r = 0; r < 4; ++r) acc[i][j][r] = 0.f;
    for (int ks = 0; ks < 16; ++ks) {
        const int k0 = ks * 32 + g * 8;
        v8s afr[2], bfr[8];
#pragma unroll
        for (int mi = 0; mi < 2; ++mi) {
            if (k0 < 256) {
                const float* ap = xA + (size_t)(bm + r0l + mi * 16) * CD + k0;
                v4f a = *reinterpret_cast<const v4f*>(ap);
                v4f b = *reinterpret_cast<const v4f*>(ap + 4);
                v8s t;
#pragma unroll
                for (int j = 0; j < 4; ++j) { t[j] = (short)f2bf(a[j]); t[j + 4] = (short)f2bf(b[j]); }
                afr[mi] = t;
            } else {
                const int row = r0l + mi * 16, kk = k0 - 256;
                afr[mi] = *reinterpret_cast<const v8s*>(&yls[row * 256 + (kk ^ ((row & 7) << 3))]);
            }
        }
#pragma unroll
        for (int ni = 0; ni < 8; ++ni)
            bfr[ni] = *reinterpret_cast<const v8s*>(W11 + (size_t)(wc * 128 + ni * 16 + q15) * 512 + k0);
#pragma unroll
        for (int mi = 0; mi < 2; ++mi)
#pragma unroll
            for (int ni = 0; ni < 8; ++ni)
                acc[mi][ni] = __builtin_amdgcn_mfma_f32_16x16x32_bf16(afr[mi], bfr[ni], acc[mi][ni], 0, 0, 0);
    }
#pragma unroll
    for (int ni = 0; ni < 8; ++ni) {
        const int col = wc * 128 + ni * 16 + q15;
        const float sc = fg[col] * rsqrtf(fv[col] + 1e-3f);
        const float tc = fbe[col] - fm[col] * sc;
        const float bia = fb[col];
#pragma unroll
        for (int mi = 0; mi < 2; ++mi)
#pragma unroll
            for (int r = 0; r < 4; ++r) {
                const int row = bm + wr * 32 + mi * 16 + g * 4 + r;
                float z = fmaxf((acc[mi][ni][r] + bia) * sc + tc, 0.f);
                out[(size_t)row * CD + col] = z;
            }
    }
}

// ---------------- launcher ---------------------------------------------------
extern "C" void kernel_launch(void* const* d_in, const int* in_sizes, int n_in,
                              void* d_out, int out_size, void* d_ws, size_t ws_size,
                              hipStream_t stream) {
    const float* f_low   = (const float*)d_in[0];
    const float* f_high  = (const float*)d_in[1];
    const float* bott_W  = (const float*)d_in[2];
    const float* bott_b  = (const float*)d_in[3];
    const float* bott_g  = (const float*)d_in[4];
    const float* bott_be = (const float*)d_in[5];
    const float* bott_m  = (const float*)d_in[6];
    const float* bott_v  = (const float*)d_in[7];
    const float* qkv_W   = (const float*)d_in[8];
    const float* qkv_g   = (const float*)d_in[9];
    const float* qkv_be  = (const float*)d_in[10];
    const float* qkv_m   = (const float*)d_in[11];
    const float* qkv_v   = (const float*)d_in[12];
    const float* mlp_W   = (const float*)d_in[13];
    const float* mlp_g   = (const float*)d_in[14];
    const float* mlp_be  = (const float*)d_in[15];
    const float* mlp_m   = (const float*)d_in[16];
    const float* mlp_v   = (const float*)d_in[17];
    const float* fus_W   = (const float*)d_in[18];
    const float* fus_b   = (const float*)d_in[19];
    const float* fus_g   = (const float*)d_in[20];
    const float* fus_be  = (const float*)d_in[21];
    const float* fus_m   = (const float*)d_in[22];
    const float* fus_v   = (const float*)d_in[23];
    (void)in_sizes; (void)n_in; (void)out_size; (void)ws_size;

    char* ws = (char*)d_ws;
    const size_t MB = 1024 * 1024;
    float* xA = (float*)(ws);                       // 16.8 MB residual stream
    ubf*   o0 = (ubf*)  (ws + 17 * MB);             // 8.4 MB attn half0 partial
    ubf*   qB = (ubf*)  (ws + 26 * MB);             // 8.4 MB Q
    ubf*   kB = (ubf*)  (ws + 35 * MB);             // 8.4 MB K
    ubf*   vT = (ubf*)  (ws + 44 * MB);             // 8.4 MB V chunk-major
    ubf*   wT = (ubf*)  (ws + 53 * MB);             // 1.7 MB, 12 transposed weights
    ubf*   o1 = (ubf*)  (ws + 56 * MB);             // 8.4 MB attn half1 partial
    float* ml = (float*)(ws + 65 * MB);             // 512 KB (m,l) x 2 halves

    k_pre<<<dim3(4096 + 1536), dim3(256), 0, stream>>>(f_low, xA,
                                                       bott_W, qkv_W, mlp_W, fus_W, wT);

    k_conv1<<<dim3(256), dim3(256), 0, stream>>>(xA, wT,
                                                 bott_b, bott_g, bott_be, bott_m, bott_v);

    k_qkv<<<dim3(128, 6), dim3(256), 0, stream>>>(xA, f_high, wT + (size_t)6 * 65536,
                                                  qkv_g, qkv_be, qkv_m, qkv_v, qB, kB, vT);

    k_attn<<<dim3(512), dim3(128), 0, stream>>>(qB, kB, vT, o0, o1, ml);

    k_tail<<<dim3(256), dim3(256), 0, stream>>>(o0, o1, ml, xA, wT,
                                                mlp_g, mlp_be, mlp_m, mlp_v,
                                                fus_b, fus_g, fus_be, fus_m, fus_v,
                                                (float*)d_out);
}